// Round 6
// baseline (221.486 us; speedup 1.0000x reference)
//
#include <hip/hip_runtime.h>
#include <hip/hip_bf16.h>
#include <stdint.h>

// MultiGraphConvLayer: H=3 heads, L=2 layers, B=16, S=512, D=512.
// Round 6: faithful m201-style 256x256 8-phase GEMM (two barriers/phase,
// wait-after-barrier, counted vmcnt(4) at ph4/ph8, region-death stage order,
// XOR slot swizzle both sides), split-K=4 gemmF, fused yt transpose in gemmB.

#define HH 3
#define LL 2
#define BB 16
#define SS 512
#define DD 512
#define FF 3072  // HH*LL*DD

typedef __attribute__((ext_vector_type(8))) short bf16x8;
typedef __attribute__((ext_vector_type(4))) float f32x4;
typedef __attribute__((ext_vector_type(4))) float vfloat4;
typedef __attribute__((ext_vector_type(4))) short shortx4;

__device__ __forceinline__ short f2b(float x) {
  union { float f; uint32_t u; } v; v.f = x;
  return (short)((v.u + 0x7FFFu + ((v.u >> 16) & 1u)) >> 16);
}
__device__ __forceinline__ float b2f(short s) {
  union { uint32_t u; float f; } v; v.u = ((uint32_t)(uint16_t)s) << 16;
  return v.f;
}

__device__ __forceinline__ void gld16(const short* g, short* l) {
  __builtin_amdgcn_global_load_lds((const __attribute__((address_space(1))) void*)g,
                                   (__attribute__((address_space(3))) void*)l, 16, 0, 0);
}

// T1: XCD-chunked blockIdx swizzle (grid divisible by 8 — all ours are).
__device__ __forceinline__ int xswz(int grid) {
  int cpx = grid >> 3;
  return (blockIdx.x & 7) * cpx + (blockIdx.x >> 3);
}

// ---- adj fp32 -> bf16, plus rdenom = 1/(rowsum+1). One wave per row of 512.
__global__ void k_cvt_adj(const float* __restrict__ adj, short* __restrict__ adjb,
                          float* __restrict__ rden) {
  int row = blockIdx.x * 4 + (threadIdx.x >> 6);
  int lane = threadIdx.x & 63;
  const float* src = adj + (size_t)row * SS;
  vfloat4 a = *(const vfloat4*)(src + lane * 8);
  vfloat4 b = *(const vfloat4*)(src + lane * 8 + 4);
  bf16x8 o;
  o[0] = f2b(a[0]); o[1] = f2b(a[1]); o[2] = f2b(a[2]); o[3] = f2b(a[3]);
  o[4] = f2b(b[0]); o[5] = f2b(b[1]); o[6] = f2b(b[2]); o[7] = f2b(b[3]);
  *(bf16x8*)(adjb + (size_t)row * SS + lane * 8) = o;
  float s = a[0]+a[1]+a[2]+a[3]+b[0]+b[1]+b[2]+b[3];
  #pragma unroll
  for (int off = 32; off > 0; off >>= 1) s += __shfl_xor(s, off);
  if (lane == 0) rden[row] = 1.0f / (s + 1.0f);
}

// ---- W_gcn and W_out fp32 -> bf16 (both 1,572,864 elements).
__global__ void k_cvt_w(const float* __restrict__ wg, const float* __restrict__ wo,
                        short* __restrict__ wgb, short* __restrict__ wob) {
  size_t i = ((size_t)blockIdx.x * 256 + threadIdx.x) * 8;
  vfloat4 a = *(const vfloat4*)(wg + i);
  vfloat4 b = *(const vfloat4*)(wg + i + 4);
  bf16x8 o;
  o[0]=f2b(a[0]); o[1]=f2b(a[1]); o[2]=f2b(a[2]); o[3]=f2b(a[3]);
  o[4]=f2b(b[0]); o[5]=f2b(b[1]); o[6]=f2b(b[2]); o[7]=f2b(b[3]);
  *(bf16x8*)(wgb + i) = o;
  a = *(const vfloat4*)(wo + i);
  b = *(const vfloat4*)(wo + i + 4);
  o[0]=f2b(a[0]); o[1]=f2b(a[1]); o[2]=f2b(a[2]); o[3]=f2b(a[3]);
  o[4]=f2b(b[0]); o[5]=f2b(b[1]); o[6]=f2b(b[2]); o[7]=f2b(b[3]);
  *(bf16x8*)(wob + i) = o;
}

// ---- gcn_inputs [B][S][D] fp32 -> X0T [B][D][S] bf16 (64x64 LDS transpose)
__global__ void k_t_x0(const float* __restrict__ x, short* __restrict__ xt) {
  __shared__ short t[64][72];
  int bid = blockIdx.x;            // BB*64
  int b = bid >> 6, q = bid & 63;
  int s0 = (q >> 3) * 64, d0 = (q & 7) * 64;
  int tid = threadIdx.x;
  int r = tid >> 4, c4 = (tid & 15) * 4;
  const float* src = x + ((size_t)b * SS + s0) * DD + d0;
  #pragma unroll
  for (int rr = 0; rr < 64; rr += 16) {
    vfloat4 v = *(const vfloat4*)(src + (size_t)(r + rr) * DD + c4);
    t[r+rr][c4+0] = f2b(v[0]); t[r+rr][c4+1] = f2b(v[1]);
    t[r+rr][c4+2] = f2b(v[2]); t[r+rr][c4+3] = f2b(v[3]);
  }
  __syncthreads();
  int dloc = tid >> 3, s8 = (tid & 7) * 8;
  short* dst = xt + (size_t)b * DD * SS + s0;
  #pragma unroll
  for (int dd = 0; dd < 64; dd += 32) {
    bf16x8 o;
    #pragma unroll
    for (int j = 0; j < 8; j++) o[j] = t[s8 + j][dloc + dd];
    *(bf16x8*)(dst + (size_t)(d0 + dloc + dd) * SS + s8) = o;
  }
}

// =====================================================================
// 256x256 8-phase GEMM core (m201 template, plain HIP).
// C = A(256 x K) * B'(256 x K)^T, NT = K/64 (even), 512 threads = 8 waves
// (2M x 4N), per-wave 128x64 output = acc[8][4] 16x16x32 frags.
// LDS 128KB shorts: region(buf,op,half) = buf*32768 + op*16384 + half*8192,
// each region 128 rows x 64 cols bf16; 16B slot s of row r holds global
// slot s^(r&7) (involution, both sides).
// Per phase: {ds-reads, 1 half-tile stage(2 gld16), [lgkm(8) if 12 reads],
// barrier, lgkm(0), setprio(1), 16 MFMA, setprio(0), barrier}.
// Quadrants per K-tile: (0,0),(0,1),(1,1),(1,0). Region-death stage order:
//  ph1 buf1.Ah0<-o  ph2 buf1.Ah1<-o  ph3 buf0.Bh0<-e2  ph4 buf0.Bh1<-e2 +VM4
//  ph5 buf0.Ah0<-e2 ph6 buf0.Ah1<-e2 ph7 buf1.Bh0<-o2  ph8 buf1.Bh1<-o2 +VM4
// vmcnt(4) leaves the 2 newest stages in flight; everything older landed.
// =====================================================================

#define BARR __builtin_amdgcn_s_barrier()
#define LG0 asm volatile("s_waitcnt lgkmcnt(0)" ::: "memory")
#define LG8 asm volatile("s_waitcnt lgkmcnt(8)" ::: "memory")
#define VM4 asm volatile("s_waitcnt vmcnt(4)" ::: "memory")

__device__ __forceinline__ void gemm256(const short* __restrict__ A, int lda,
                                        const short* __restrict__ Bm, int ldb,
                                        int NT, short* lds, f32x4 acc[8][4]) {
  const int tid = threadIdx.x;
  const int lane = tid & 63, wid = tid >> 6;
  const int wr = wid >> 2, wc = wid & 3;
  const int lr = lane & 15, lk = lane >> 4;
  const int sw0 = ((lk ^ (lr & 7)) << 3);
  const int sw1 = (((4 + lk) ^ (lr & 7)) << 3);
  const short* pA = lds + wr * 8192 + lr * 64;
  const short* pB = lds + 16384 + (wc >> 1) * 8192 + (wc & 1) * 4096 + lr * 64;
  const int ssc = (((tid & 7) ^ ((tid >> 3) & 7)) << 3);
  const short* gA0 = A + (size_t)(tid >> 3) * lda + ssc;
  const short* gA1 = gA0 + (size_t)128 * lda;
  const short* gB0 = Bm + (size_t)(tid >> 3) * ldb + ssc;
  const short* gB1 = gB0 + (size_t)128 * ldb;

#define ST(gp, ld_, reg_, kt) do { \
    const short* g_ = (gp) + (size_t)(kt) * 64; \
    short* d_ = lds + (reg_) + tid * 8; \
    gld16(g_, d_); gld16(g_ + (size_t)64 * (ld_), d_ + 4096); } while (0)

  bf16x8 av[4][2], bv[2][2][2];

#define RDA(base, mh) do { \
    _Pragma("unroll") for (int mm = 0; mm < 4; mm++) { \
      av[mm][0] = *(const bf16x8*)((base) + (mh) * 4096 + mm * 1024 + sw0); \
      av[mm][1] = *(const bf16x8*)((base) + (mh) * 4096 + mm * 1024 + sw1); \
    } } while (0)
#define RDB(base, nh) do { \
    _Pragma("unroll") for (int nn = 0; nn < 2; nn++) { \
      bv[nh][nn][0] = *(const bf16x8*)((base) + (nh) * 2048 + nn * 1024 + sw0); \
      bv[nh][nn][1] = *(const bf16x8*)((base) + (nh) * 2048 + nn * 1024 + sw1); \
    } } while (0)
#define QUAD(mh, nh) do { \
    __builtin_amdgcn_s_setprio(1); \
    _Pragma("unroll") for (int mm = 0; mm < 4; mm++) \
    _Pragma("unroll") for (int nn = 0; nn < 2; nn++) \
    _Pragma("unroll") for (int kk = 0; kk < 2; kk++) \
      acc[(mh)*4+mm][(nh)*2+nn] = __builtin_amdgcn_mfma_f32_16x16x32_bf16( \
          av[mm][kk], bv[nh][nn][kk], acc[(mh)*4+mm][(nh)*2+nn], 0, 0, 0); \
    __builtin_amdgcn_s_setprio(0); } while (0)

  // prologue: buf0 <- tile0 (4 halves), buf1.B <- tile1 (2 halves).
  ST(gA0, lda, 0, 0);            ST(gA1, lda, 8192, 0);
  ST(gB0, ldb, 16384, 0);        ST(gB1, ldb, 24576, 0);
  ST(gB0, ldb, 32768+16384, 1);  ST(gB1, ldb, 32768+24576, 1);
  VM4;   // buf0's 8 loads landed; buf1.B (newest 4) may pend
  BARR;

  const int IT = NT >> 1;
  for (int j = 0; j < IT; j++) {
    int o  = 2*j + 1;
    int e2 = 2*j + 2; if (e2 >= NT) e2 -= NT;
    int o2 = 2*j + 3; if (o2 >= NT) o2 -= NT;
    // ---- E tile (buf0) ----
    // ph1
    RDA(pA, 0); RDB(pB, 0);
    ST(gA0, lda, 32768, o);
    LG8;
    BARR; LG0; QUAD(0, 0); BARR;
    // ph2
    RDB(pB, 1);
    ST(gA1, lda, 32768+8192, o);
    BARR; LG0; QUAD(0, 1); BARR;
    // ph3
    RDA(pA, 1);
    ST(gB0, ldb, 16384, e2);
    BARR; LG0; QUAD(1, 1); BARR;
    // ph4
    ST(gB1, ldb, 16384+8192, e2);
    VM4;
    BARR; QUAD(1, 0); BARR;
    // ---- O tile (buf1) ----
    // ph5
    RDA(pA + 32768, 0); RDB(pB + 32768, 0);
    ST(gA0, lda, 0, e2);
    LG8;
    BARR; LG0; QUAD(0, 0); BARR;
    // ph6
    RDB(pB + 32768, 1);
    ST(gA1, lda, 8192, e2);
    BARR; LG0; QUAD(0, 1); BARR;
    // ph7
    RDA(pA + 32768, 1);
    ST(gB0, ldb, 32768+16384, o2);
    BARR; LG0; QUAD(1, 1); BARR;
    // ph8
    ST(gB1, ldb, 32768+16384+8192, o2);
    VM4;
    BARR; QUAD(1, 0); BARR;
  }
  // drain wrapped tail stages before LDS deallocates at block end
  asm volatile("s_waitcnt vmcnt(0)" ::: "memory");
#undef ST
#undef RDA
#undef RDB
#undef QUAD
}

// ---- kA: AxpX[hb] = adj_hb @ X_{h,layer} + X   (bf16 out)
__global__ __launch_bounds__(512, 2) void k2_gemmA(
    const short* __restrict__ adjb, const short* __restrict__ xtp,
    const float* __restrict__ x0f, const short* __restrict__ finb,
    int layer, short* __restrict__ axpx) {
  extern __shared__ short lds[];
  int bx = xswz(HH * BB * 4);
  int hb = bx >> 2, q = bx & 3;
  int h = hb / BB, b = hb % BB;
  int tr = q >> 1, tc = q & 1;
  const short* A = adjb + (size_t)hb * SS * SS + (size_t)(tr * 256) * SS;
  const short* Bm = (layer == 0)
      ? xtp + (size_t)b * DD * SS + (size_t)(tc * 256) * SS
      : xtp + (size_t)hb * DD * SS + (size_t)(tc * 256) * SS;
  f32x4 acc[8][4];
  #pragma unroll
  for (int m = 0; m < 8; m++)
    #pragma unroll
    for (int n = 0; n < 4; n++) acc[m][n] = (f32x4){0.f, 0.f, 0.f, 0.f};
  gemm256(A, SS, Bm, SS, SS / 64, lds, acc);
  int lane = threadIdx.x & 63, wid = threadIdx.x >> 6;
  int wr = wid >> 2, wc = wid & 3;
  int lr = lane & 15, lk = lane >> 4;
  short* outp = axpx + (size_t)hb * SS * DD;
  #pragma unroll
  for (int m = 0; m < 8; m++) {
    #pragma unroll
    for (int n = 0; n < 4; n++) {
      #pragma unroll
      for (int r = 0; r < 4; r++) {
        int s = tr * 256 + wr * 128 + m * 16 + lk * 4 + r;
        int d = tc * 256 + wc * 64 + n * 16 + lr;
        float add = (layer == 0)
            ? x0f[((size_t)b * SS + s) * DD + d]
            : b2f(finb[((size_t)b * SS + s) * FF + (size_t)(h * LL) * DD + d]);
        outp[(size_t)s * DD + d] = f2b(acc[m][n][r] + add);
      }
    }
  }
}

// ---- kB: Y = relu((AxpX @ W^T + 2b) * rdenom) -> finb; layer0 also -> yt^T
__global__ __launch_bounds__(512, 2) void k2_gemmB(
    const short* __restrict__ axpx, const short* __restrict__ wgb,
    const float* __restrict__ bg, const float* __restrict__ rden,
    int layer, short* __restrict__ finb, short* __restrict__ yt) {
  extern __shared__ short lds[];
  int bx = xswz(HH * BB * 4);
  int hb = bx >> 2, q = bx & 3;
  int h = hb / BB, b = hb % BB;
  int tr = q >> 1, tc = q & 1;
  int idx = h * LL + layer;
  const short* A = axpx + (size_t)hb * SS * DD + (size_t)(tr * 256) * DD;
  const short* Bm = wgb + (size_t)idx * DD * DD + (size_t)(tc * 256) * DD;
  f32x4 acc[8][4];
  #pragma unroll
  for (int m = 0; m < 8; m++)
    #pragma unroll
    for (int n = 0; n < 4; n++) acc[m][n] = (f32x4){0.f, 0.f, 0.f, 0.f};
  gemm256(A, DD, Bm, DD, DD / 64, lds, acc);
  int lane = threadIdx.x & 63, wid = threadIdx.x >> 6;
  int wr = wid >> 2, wc = wid & 3;
  int lr = lane & 15, lk = lane >> 4;
  #pragma unroll
  for (int m = 0; m < 8; m++) {
    #pragma unroll
    for (int n = 0; n < 4; n++) {
      shortx4 tp;
      #pragma unroll
      for (int r = 0; r < 4; r++) {
        int s = tr * 256 + wr * 128 + m * 16 + lk * 4 + r;
        int e = tc * 256 + wc * 64 + n * 16 + lr;
        float v = (acc[m][n][r] + 2.0f * bg[(size_t)idx * DD + e])
                  * rden[(size_t)hb * SS + s];
        v = fmaxf(v, 0.0f);
        short bw = f2b(v);
        finb[((size_t)b * SS + s) * FF + (size_t)idx * DD + e] = bw;
        tp[r] = bw;
      }
      if (layer == 0) {
        int sb = tr * 256 + wr * 128 + m * 16 + lk * 4;
        int e = tc * 256 + wc * 64 + n * 16 + lr;
        *(shortx4*)(yt + (size_t)hb * DD * SS + (size_t)e * SS + sb) = tp;
      }
    }
  }
}

// ---- kF (split-K=4): part[ks] = finb[:, ks*768+..] @ W_out[:, same]^T
__global__ __launch_bounds__(512, 2) void k2_gemmF(
    const short* __restrict__ finb, const short* __restrict__ wob,
    float* __restrict__ part) {
  extern __shared__ short lds[];
  int bx = xswz(256);
  int ks = bx >> 6, q = bx & 63;
  int tr = q >> 1, tc = q & 1;       // tr 0..31 (8192 rows), tc 0..1
  const short* A = finb + (size_t)(tr * 256) * FF + ks * 768;
  const short* Bm = wob + (size_t)(tc * 256) * FF + ks * 768;
  f32x4 acc[8][4];
  #pragma unroll
  for (int m = 0; m < 8; m++)
    #pragma unroll
    for (int n = 0; n < 4; n++) acc[m][n] = (f32x4){0.f, 0.f, 0.f, 0.f};
  gemm256(A, FF, Bm, FF, 768 / 64, lds, acc);
  int lane = threadIdx.x & 63, wid = threadIdx.x >> 6;
  int wr = wid >> 2, wc = wid & 3;
  int lr = lane & 15, lk = lane >> 4;
  float* op = part + (size_t)ks * ((size_t)BB * SS * DD);
  #pragma unroll
  for (int m = 0; m < 8; m++) {
    #pragma unroll
    for (int n = 0; n < 4; n++) {
      #pragma unroll
      for (int r = 0; r < 4; r++) {
        int row = tr * 256 + wr * 128 + m * 16 + lk * 4 + r;
        int d = tc * 256 + wc * 64 + n * 16 + lr;
        op[(size_t)row * DD + d] = acc[m][n][r];
      }
    }
  }
}

// ---- reduce: out = x0 + b_out + sum_ks part[ks]   (grid-stride, float4)
__global__ void k_redF(const float* __restrict__ part, const float* __restrict__ x0f,
                       const float* __restrict__ bo, float* __restrict__ out) {
  const size_t PSZ = (size_t)BB * SS * DD;
  const size_t NV = PSZ / 4;
  for (size_t v = (size_t)blockIdx.x * 256 + threadIdx.x; v < NV;
       v += (size_t)gridDim.x * 256) {
    size_t i = v * 4;
    int d = (int)(i & (DD - 1));
    vfloat4 s = *(const vfloat4*)(part + i);
    s += *(const vfloat4*)(part + PSZ + i);
    s += *(const vfloat4*)(part + 2*PSZ + i);
    s += *(const vfloat4*)(part + 3*PSZ + i);
    s += *(const vfloat4*)(x0f + i);
    s += *(const vfloat4*)(bo + d);
    *(vfloat4*)(out + i) = s;
  }
}

extern "C" void kernel_launch(void* const* d_in, const int* in_sizes, int n_in,
                              void* d_out, int out_size, void* d_ws, size_t ws_size,
                              hipStream_t stream) {
  const float* adj = (const float*)d_in[0];
  const float* x0  = (const float*)d_in[1];
  // d_in[2], d_in[3]: mask / domain_mask — unused by the reference forward.
  const float* wg  = (const float*)d_in[4];
  const float* bg  = (const float*)d_in[5];
  const float* wo  = (const float*)d_in[6];
  const float* bo  = (const float*)d_in[7];
  float* out = (float*)d_out;

  char* p = (char*)d_ws;
  short* adjb = (short*)p; p += (size_t)HH*BB*SS*SS*2;   // 25,165,824
  short* x0t  = (short*)p; p += (size_t)BB*DD*SS*2;      //  8,388,608
  short* yt   = (short*)p; p += (size_t)HH*BB*DD*SS*2;   // 25,165,824
  short* axpx = (short*)p; p += (size_t)HH*BB*SS*DD*2;   // 25,165,824
  short* finb = (short*)p; p += (size_t)BB*SS*FF*2;      // 50,331,648
  short* wgb  = (short*)p; p += (size_t)HH*LL*DD*DD*2;   //  3,145,728
  short* wob  = (short*)p; p += (size_t)DD*FF*2;         //  3,145,728
  float* rden = (float*)p;                               //     98,304
  // split-K partials (64 MB) reuse adjb..axpx (83.9 MB) — dead by gemmF time
  float* part = (float*)d_ws;

  hipFuncSetAttribute((const void*)k2_gemmA,
                      hipFuncAttributeMaxDynamicSharedMemorySize, 131072);
  hipFuncSetAttribute((const void*)k2_gemmB,
                      hipFuncAttributeMaxDynamicSharedMemorySize, 131072);
  hipFuncSetAttribute((const void*)k2_gemmF,
                      hipFuncAttributeMaxDynamicSharedMemorySize, 131072);

  k_cvt_adj<<<HH*BB*SS/4, 256, 0, stream>>>(adj, adjb, rden);
  k_cvt_w<<<768, 256, 0, stream>>>(wg, wo, wgb, wob);
  k_t_x0<<<BB*64, 256, 0, stream>>>(x0, x0t);

  // layer 0
  k2_gemmA<<<HH*BB*4, 512, 131072, stream>>>(adjb, x0t, x0, finb, 0, axpx);
  k2_gemmB<<<HH*BB*4, 512, 131072, stream>>>(axpx, wgb, bg, rden, 0, finb, yt);
  // layer 1 (gemmB layer-0 epilogue wrote yt = transposed layer-0 outputs)
  k2_gemmA<<<HH*BB*4, 512, 131072, stream>>>(adjb, yt, x0, finb, 1, axpx);
  k2_gemmB<<<HH*BB*4, 512, 131072, stream>>>(axpx, wgb, bg, rden, 1, finb, yt);
  // output projection (split-K=4) + fused reduce w/ bias + residual
  k2_gemmF<<<256, 512, 131072, stream>>>(finb, wob, part);
  k_redF<<<2048, 256, 0, stream>>>(part, x0, bo, out);
}

// Round 7
// 207.456 us; speedup vs baseline: 1.0676x; 1.0676x over previous
//
#include <hip/hip_runtime.h>
#include <hip/hip_bf16.h>
#include <stdint.h>

// MultiGraphConvLayer: H=3 heads, L=2 layers, B=16, S=512, D=512.
// Round 7: 128^2 2-phase core deepened to 4 buffers / lead-3 / vmcnt(8)
// (latency cover for streaming operands), b-major gemmA grouping,
// bf16 x0 for gemmA epilogue, split-K=2 gemmF, fused yt transpose in gemmB.

#define HH 3
#define LL 2
#define BB 16
#define SS 512
#define DD 512
#define FF 3072  // HH*LL*DD

typedef __attribute__((ext_vector_type(8))) short bf16x8;
typedef __attribute__((ext_vector_type(4))) float f32x4;
typedef __attribute__((ext_vector_type(4))) float vfloat4;
typedef __attribute__((ext_vector_type(4))) short shortx4;

__device__ __forceinline__ short f2b(float x) {
  union { float f; uint32_t u; } v; v.f = x;
  return (short)((v.u + 0x7FFFu + ((v.u >> 16) & 1u)) >> 16);
}
__device__ __forceinline__ float b2f(short s) {
  union { uint32_t u; float f; } v; v.u = ((uint32_t)(uint16_t)s) << 16;
  return v.f;
}

__device__ __forceinline__ void gld16(const short* g, short* l) {
  __builtin_amdgcn_global_load_lds((const __attribute__((address_space(1))) void*)g,
                                   (__attribute__((address_space(3))) void*)l, 16, 0, 0);
}

// T1: XCD-chunked blockIdx swizzle (grid divisible by 8 — all ours are).
__device__ __forceinline__ int xswz(int grid) {
  int cpx = grid >> 3;
  return (blockIdx.x & 7) * cpx + (blockIdx.x >> 3);
}

// ---- adj fp32 -> bf16, plus rdenom = 1/(rowsum+1). One wave per row of 512.
__global__ void k_cvt_adj(const float* __restrict__ adj, short* __restrict__ adjb,
                          float* __restrict__ rden) {
  int row = blockIdx.x * 4 + (threadIdx.x >> 6);
  int lane = threadIdx.x & 63;
  const float* src = adj + (size_t)row * SS;
  vfloat4 a = *(const vfloat4*)(src + lane * 8);
  vfloat4 b = *(const vfloat4*)(src + lane * 8 + 4);
  bf16x8 o;
  o[0] = f2b(a[0]); o[1] = f2b(a[1]); o[2] = f2b(a[2]); o[3] = f2b(a[3]);
  o[4] = f2b(b[0]); o[5] = f2b(b[1]); o[6] = f2b(b[2]); o[7] = f2b(b[3]);
  *(bf16x8*)(adjb + (size_t)row * SS + lane * 8) = o;
  float s = a[0]+a[1]+a[2]+a[3]+b[0]+b[1]+b[2]+b[3];
  #pragma unroll
  for (int off = 32; off > 0; off >>= 1) s += __shfl_xor(s, off);
  if (lane == 0) rden[row] = 1.0f / (s + 1.0f);
}

// ---- W_gcn and W_out fp32 -> bf16 (both 1,572,864 elements).
__global__ void k_cvt_w(const float* __restrict__ wg, const float* __restrict__ wo,
                        short* __restrict__ wgb, short* __restrict__ wob) {
  size_t i = ((size_t)blockIdx.x * 256 + threadIdx.x) * 8;
  vfloat4 a = *(const vfloat4*)(wg + i);
  vfloat4 b = *(const vfloat4*)(wg + i + 4);
  bf16x8 o;
  o[0]=f2b(a[0]); o[1]=f2b(a[1]); o[2]=f2b(a[2]); o[3]=f2b(a[3]);
  o[4]=f2b(b[0]); o[5]=f2b(b[1]); o[6]=f2b(b[2]); o[7]=f2b(b[3]);
  *(bf16x8*)(wgb + i) = o;
  a = *(const vfloat4*)(wo + i);
  b = *(const vfloat4*)(wo + i + 4);
  o[0]=f2b(a[0]); o[1]=f2b(a[1]); o[2]=f2b(a[2]); o[3]=f2b(a[3]);
  o[4]=f2b(b[0]); o[5]=f2b(b[1]); o[6]=f2b(b[2]); o[7]=f2b(b[3]);
  *(bf16x8*)(wob + i) = o;
}

// ---- gcn_inputs [B][S][D] fp32 -> X0T [B][D][S] bf16 + row-major x0b bf16
__global__ void k_t_x0(const float* __restrict__ x, short* __restrict__ xt,
                       short* __restrict__ x0b) {
  __shared__ short t[64][72];
  int bid = blockIdx.x;            // BB*64
  int b = bid >> 6, q = bid & 63;
  int s0 = (q >> 3) * 64, d0 = (q & 7) * 64;
  int tid = threadIdx.x;
  int r = tid >> 4, c4 = (tid & 15) * 4;
  const float* src = x + ((size_t)b * SS + s0) * DD + d0;
  #pragma unroll
  for (int rr = 0; rr < 64; rr += 16) {
    vfloat4 v = *(const vfloat4*)(src + (size_t)(r + rr) * DD + c4);
    shortx4 o4;
    o4[0] = f2b(v[0]); o4[1] = f2b(v[1]); o4[2] = f2b(v[2]); o4[3] = f2b(v[3]);
    t[r+rr][c4+0] = o4[0]; t[r+rr][c4+1] = o4[1];
    t[r+rr][c4+2] = o4[2]; t[r+rr][c4+3] = o4[3];
    *(shortx4*)(x0b + ((size_t)b * SS + s0 + r + rr) * DD + d0 + c4) = o4;
  }
  __syncthreads();
  int dloc = tid >> 3, s8 = (tid & 7) * 8;
  short* dst = xt + (size_t)b * DD * SS + s0;
  #pragma unroll
  for (int dd = 0; dd < 64; dd += 32) {
    bf16x8 o;
    #pragma unroll
    for (int j = 0; j < 8; j++) o[j] = t[s8 + j][dloc + dd];
    *(bf16x8*)(dst + (size_t)(d0 + dloc + dd) * SS + s8) = o;
  }
}

// ---- one K=32 sub-step from a row-major [128][32] LDS tile with XOR-swizzled
// 16B slots: LDS (row, s) holds global (row, s ^ ((row>>1)&3)).
// Per-lane read slot kgs = (lane>>4) ^ ((lane&15)>>1)&3 -> <=2-way (free).
__device__ __forceinline__ void compute32(const short* As, const short* Bs,
                                          int wr, int wc, int lrow, int kgs,
                                          f32x4 acc[4][4]) {
  bf16x8 af[4], bv[4];
  #pragma unroll
  for (int m = 0; m < 4; m++)
    af[m] = *(const bf16x8*)(As + (wr*64 + m*16 + lrow) * 32 + kgs);
  #pragma unroll
  for (int n = 0; n < 4; n++)
    bv[n] = *(const bf16x8*)(Bs + (wc*64 + n*16 + lrow) * 32 + kgs);
  #pragma unroll
  for (int m = 0; m < 4; m++)
    #pragma unroll
    for (int n = 0; n < 4; n++)
      acc[m][n] = __builtin_amdgcn_mfma_f32_16x16x32_bf16(af[m], bv[n], acc[m][n], 0, 0, 0);
}

// ---- NT GEMM core: 4-buffer, lead-3, counted vmcnt(8), one raw barrier/step.
// C(128x128) = A(128xK, lda) * B'(128xK, ldb)^T; 4 waves, 64x64 each.
// LDS: 4 bufs x (As 4096 | Bs 4096) shorts = 64KB -> 2 blocks/CU.
// Steady state: 12 loads in flight (tiles t,t+1,t+2); vmcnt(8) retires the
// oldest 4 (tile t, issued 3 steps = ~1900cy earlier -> HBM latency covered).
// Slot (t+3)%4 rewritten at iter t = slot of tile t-1, whose ds_reads every
// wave completed (consumed by MFMA) before passing this iteration's barrier.
__device__ __forceinline__ void gemm2ph(const short* __restrict__ A, int lda,
                                        const short* __restrict__ Bm, int ldb,
                                        int K, short* lds, f32x4 acc[4][4]) {
  int tid = threadIdx.x;
  int lane = tid & 63, wid = tid >> 6;
  int wr = wid >> 1, wc = wid & 1;
  int lrow = lane & 15;
  int kgs = (((lane >> 4) ^ ((lane >> 1) & 3)) << 3);
  int gcol = (((tid & 3) ^ ((tid >> 3) & 3)) << 3);
  const short* ga = A + (size_t)(tid >> 2) * lda + gcol;
  const short* gb = Bm + (size_t)(tid >> 2) * ldb + gcol;

  #define STAGE(BUF, k0) do { \
    short* as_ = (BUF); short* bs_ = (BUF) + 4096; \
    gld16(ga + (k0), as_ + tid*8); \
    gld16(ga + (k0) + (size_t)64 * lda, as_ + 2048 + tid*8); \
    gld16(gb + (k0), bs_ + tid*8); \
    gld16(gb + (k0) + (size_t)64 * ldb, bs_ + 2048 + tid*8); \
  } while (0)
  #define STEP(VM) do { \
    asm volatile("s_waitcnt vmcnt(" #VM ")" ::: "memory"); \
    __builtin_amdgcn_s_barrier(); \
    __builtin_amdgcn_sched_barrier(0); \
  } while (0)
  #define ROT do { short* tmp_ = p0; p0 = p1; p1 = p2; p2 = p3; p3 = tmp_; } while (0)

  short* p0 = lds;
  short* p1 = lds + 8192;
  short* p2 = lds + 16384;
  short* p3 = lds + 24576;
  int NT = K / 32;                 // >= 4 everywhere here (16 or 48)
  STAGE(p0, 0);
  STAGE(p1, 32);
  STAGE(p2, 64);
  for (int t = 0; t < NT - 3; t++) {
    STEP(8);
    STAGE(p3, (t + 3) * 32);
    compute32(p0, p0 + 4096, wr, wc, lrow, kgs, acc);
    ROT;
  }
  STEP(8); compute32(p0, p0 + 4096, wr, wc, lrow, kgs, acc); ROT;
  STEP(4); compute32(p0, p0 + 4096, wr, wc, lrow, kgs, acc); ROT;
  STEP(0); compute32(p0, p0 + 4096, wr, wc, lrow, kgs, acc);
  #undef STAGE
  #undef STEP
  #undef ROT
}

// ---- kA: AxpX[hb] = adj_hb @ X_{h,layer} + X   (bf16 out)
__global__ __launch_bounds__(256, 2) void k_gemmA(
    const short* __restrict__ adjb, const short* __restrict__ xtp,
    const short* __restrict__ x0b, const short* __restrict__ finb,
    int layer, short* __restrict__ axpx) {
  extern __shared__ short lds[];
  int bx = xswz(HH*BB*16);
  int q = bx & 15;
  int g = bx >> 4;                 // b-major grouping: g = b*3 + h
  int b = g / 3, h = g - b * 3;
  int hb = h * BB + b;
  int tr = q >> 2, tc = q & 3;
  const short* A = adjb + (size_t)hb * SS * SS + (size_t)(tr * 128) * SS;
  const short* Bm = (layer == 0)
      ? xtp + (size_t)b * DD * SS + (size_t)(tc * 128) * SS
      : xtp + (size_t)hb * DD * SS + (size_t)(tc * 128) * SS;
  f32x4 acc[4][4];
  #pragma unroll
  for (int m = 0; m < 4; m++)
    #pragma unroll
    for (int n = 0; n < 4; n++) acc[m][n] = (f32x4){0.f, 0.f, 0.f, 0.f};
  gemm2ph(A, SS, Bm, SS, SS, lds, acc);
  int lane = threadIdx.x & 63, wid = threadIdx.x >> 6;
  int wr = wid >> 1, wc = wid & 1;
  int r4 = (lane >> 4) * 4, cn = lane & 15;
  short* outp = axpx + (size_t)hb * SS * DD;
  #pragma unroll
  for (int m = 0; m < 4; m++) {
    #pragma unroll
    for (int n = 0; n < 4; n++) {
      #pragma unroll
      for (int r = 0; r < 4; r++) {
        int s = tr*128 + wr*64 + m*16 + r4 + r;
        int d = tc*128 + wc*64 + n*16 + cn;
        float add = (layer == 0)
            ? b2f(x0b[((size_t)b * SS + s) * DD + d])
            : b2f(finb[((size_t)b * SS + s) * FF + (size_t)(h * LL) * DD + d]);
        outp[(size_t)s * DD + d] = f2b(acc[m][n][r] + add);
      }
    }
  }
}

// ---- kB: Y = relu((AxpX @ W^T + 2b) * rdenom) -> finb; layer0 also -> yt^T
__global__ __launch_bounds__(256, 2) void k_gemmB(
    const short* __restrict__ axpx, const short* __restrict__ wgb,
    const float* __restrict__ bg, const float* __restrict__ rden,
    int layer, short* __restrict__ finb, short* __restrict__ yt) {
  extern __shared__ short lds[];
  int bx = xswz(HH*BB*16);
  int hb = bx >> 4, q = bx & 15;
  int h = hb / BB, b = hb % BB;
  int tr = q >> 2, tc = q & 3;
  int idx = h * LL + layer;
  const short* A = axpx + (size_t)hb * SS * DD + (size_t)(tr * 128) * DD;
  const short* Bm = wgb + (size_t)idx * DD * DD + (size_t)(tc * 128) * DD;
  f32x4 acc[4][4];
  #pragma unroll
  for (int m = 0; m < 4; m++)
    #pragma unroll
    for (int n = 0; n < 4; n++) acc[m][n] = (f32x4){0.f, 0.f, 0.f, 0.f};
  gemm2ph(A, DD, Bm, DD, DD, lds, acc);
  int lane = threadIdx.x & 63, wid = threadIdx.x >> 6;
  int wr = wid >> 1, wc = wid & 1;
  int r4 = (lane >> 4) * 4, cn = lane & 15;
  #pragma unroll
  for (int m = 0; m < 4; m++) {
    #pragma unroll
    for (int n = 0; n < 4; n++) {
      shortx4 tp;
      #pragma unroll
      for (int r = 0; r < 4; r++) {
        int s = tr*128 + wr*64 + m*16 + r4 + r;
        int e = tc*128 + wc*64 + n*16 + cn;
        float v = (acc[m][n][r] + 2.0f * bg[(size_t)idx * DD + e])
                  * rden[(size_t)hb * SS + s];
        v = fmaxf(v, 0.0f);
        short bw = f2b(v);
        finb[((size_t)b * SS + s) * FF + (size_t)idx * DD + e] = bw;
        tp[r] = bw;
      }
      if (layer == 0) {
        int sb = tr*128 + wr*64 + m*16 + r4;
        int e = tc*128 + wc*64 + n*16 + cn;
        *(shortx4*)(yt + (size_t)hb * DD * SS + (size_t)e * SS + sb) = tp;
      }
    }
  }
}

// ---- kF (split-K=2): part[ks] = finb[:, ks*1536+..] @ W_out[:, same]^T
__global__ __launch_bounds__(256, 2) void k_gemmF(
    const short* __restrict__ finb, const short* __restrict__ wob,
    float* __restrict__ part) {
  extern __shared__ short lds[];
  int bx = xswz(BB*16*2);          // 512 blocks
  int ks = bx >> 8;                // 0..1
  int q = bx & 255;
  int tr = q >> 2, tc = q & 3;     // tr 0..63, tc 0..3
  const short* A = finb + (size_t)(tr * 128) * FF + ks * 1536;
  const short* Bm = wob + (size_t)(tc * 128) * FF + ks * 1536;
  f32x4 acc[4][4];
  #pragma unroll
  for (int m = 0; m < 4; m++)
    #pragma unroll
    for (int n = 0; n < 4; n++) acc[m][n] = (f32x4){0.f, 0.f, 0.f, 0.f};
  gemm2ph(A, FF, Bm, FF, 1536, lds, acc);
  int lane = threadIdx.x & 63, wid = threadIdx.x >> 6;
  int wr = wid >> 1, wc = wid & 1;
  int r4 = (lane >> 4) * 4, cn = lane & 15;
  float* op = part + (size_t)ks * ((size_t)BB*SS*DD);
  #pragma unroll
  for (int m = 0; m < 4; m++) {
    #pragma unroll
    for (int n = 0; n < 4; n++) {
      #pragma unroll
      for (int r = 0; r < 4; r++) {
        int row = tr*128 + wr*64 + m*16 + r4 + r;
        int d = tc*128 + wc*64 + n*16 + cn;
        op[(size_t)row * DD + d] = acc[m][n][r];
      }
    }
  }
}

// ---- reduce: out = x0 + b_out + sum_ks part[ks]   (grid-stride, float4)
__global__ void k_redF(const float* __restrict__ part, const float* __restrict__ x0f,
                       const float* __restrict__ bo, float* __restrict__ out) {
  const size_t PSZ = (size_t)BB * SS * DD;
  const size_t NV = PSZ / 4;
  for (size_t v = (size_t)blockIdx.x * 256 + threadIdx.x; v < NV;
       v += (size_t)gridDim.x * 256) {
    size_t i = v * 4;
    int d = (int)(i & (DD - 1));
    vfloat4 s = *(const vfloat4*)(part + i);
    s += *(const vfloat4*)(part + PSZ + i);
    s += *(const vfloat4*)(x0f + i);
    s += *(const vfloat4*)(bo + d);
    *(vfloat4*)(out + i) = s;
  }
}

extern "C" void kernel_launch(void* const* d_in, const int* in_sizes, int n_in,
                              void* d_out, int out_size, void* d_ws, size_t ws_size,
                              hipStream_t stream) {
  const float* adj = (const float*)d_in[0];
  const float* x0  = (const float*)d_in[1];
  // d_in[2], d_in[3]: mask / domain_mask — unused by the reference forward.
  const float* wg  = (const float*)d_in[4];
  const float* bg  = (const float*)d_in[5];
  const float* wo  = (const float*)d_in[6];
  const float* bo  = (const float*)d_in[7];
  float* out = (float*)d_out;

  char* p = (char*)d_ws;
  short* adjb = (short*)p; p += (size_t)HH*BB*SS*SS*2;   // 25,165,824
  short* x0t  = (short*)p; p += (size_t)BB*DD*SS*2;      //  8,388,608
  short* yt   = (short*)p; p += (size_t)HH*BB*DD*SS*2;   // 25,165,824
  short* axpx = (short*)p; p += (size_t)HH*BB*SS*DD*2;   // 25,165,824
  short* finb = (short*)p; p += (size_t)BB*SS*FF*2;      // 50,331,648
  short* wgb  = (short*)p; p += (size_t)HH*LL*DD*DD*2;   //  3,145,728
  short* wob  = (short*)p; p += (size_t)DD*FF*2;         //  3,145,728
  float* rden = (float*)p; p += (size_t)HH*BB*SS*4;      //     98,304
  short* x0b  = (short*)p; p += (size_t)BB*SS*DD*2;      // 16,777,216
  // split-K=2 partials (32 MiB) overlay adjb+x0t (32 MiB) — dead by gemmF time
  float* part = (float*)d_ws;

  hipFuncSetAttribute((const void*)k_gemmA,
                      hipFuncAttributeMaxDynamicSharedMemorySize, 65536);
  hipFuncSetAttribute((const void*)k_gemmB,
                      hipFuncAttributeMaxDynamicSharedMemorySize, 65536);
  hipFuncSetAttribute((const void*)k_gemmF,
                      hipFuncAttributeMaxDynamicSharedMemorySize, 65536);

  k_cvt_adj<<<HH*BB*SS/4, 256, 0, stream>>>(adj, adjb, rden);
  k_cvt_w<<<768, 256, 0, stream>>>(wg, wo, wgb, wob);
  k_t_x0<<<BB*64, 256, 0, stream>>>(x0, x0t, x0b);

  // layer 0
  k_gemmA<<<HH*BB*16, 256, 65536, stream>>>(adjb, x0t, x0b, finb, 0, axpx);
  k_gemmB<<<HH*BB*16, 256, 65536, stream>>>(axpx, wgb, bg, rden, 0, finb, yt);
  // layer 1 (gemmB layer-0 epilogue wrote yt = transposed layer-0 outputs)
  k_gemmA<<<HH*BB*16, 256, 65536, stream>>>(adjb, yt, x0b, finb, 1, axpx);
  k_gemmB<<<HH*BB*16, 256, 65536, stream>>>(axpx, wgb, bg, rden, 1, finb, yt);
  // output projection (split-K=2) + fused reduce w/ bias + residual
  k_gemmF<<<BB*16*2, 256, 65536, stream>>>(finb, wob, part);
  k_redF<<<2048, 256, 0, stream>>>(part, x0, bo, out);
}

// Round 8
// 174.149 us; speedup vs baseline: 1.2718x; 1.1913x over previous
//
#include <hip/hip_runtime.h>
#include <hip/hip_bf16.h>
#include <stdint.h>

// MultiGraphConvLayer: H=3 heads, L=2 layers, B=16, S=512, D=512.
// Round 8: fp8(e4m3) streaming GEMMs. adj/x0t/yt/finb/wob stored fp8
// (y,w scaled x64); gemmA+gemmF use fp8 MFMA core (4x8KB bufs, lead-3,
// vmcnt(4), 4-5 blocks/CU); gemmB stays bf16 (R5 triple-buffer core).

#define HH 3
#define LL 2
#define BB 16
#define SS 512
#define DD 512
#define FF 3072  // HH*LL*DD

typedef __attribute__((ext_vector_type(8))) short bf16x8;
typedef __attribute__((ext_vector_type(4))) float f32x4;
typedef __attribute__((ext_vector_type(4))) float vfloat4;
typedef __attribute__((ext_vector_type(4))) short shortx4;
typedef __attribute__((ext_vector_type(2))) unsigned int uint2v;

__device__ __forceinline__ short f2b(float x) {
  union { float f; uint32_t u; } v; v.f = x;
  return (short)((v.u + 0x7FFFu + ((v.u >> 16) & 1u)) >> 16);
}
__device__ __forceinline__ float b2f(short s) {
  union { uint32_t u; float f; } v; v.u = ((uint32_t)(uint16_t)s) << 16;
  return v.f;
}
__device__ __forceinline__ float c8(uint8_t b) {
  return __builtin_amdgcn_cvt_f32_fp8((int)b, 0);
}

__device__ __forceinline__ void gld16(const short* g, short* l) {
  __builtin_amdgcn_global_load_lds((const __attribute__((address_space(1))) void*)g,
                                   (__attribute__((address_space(3))) void*)l, 16, 0, 0);
}
__device__ __forceinline__ void gld16b(const uint8_t* g, uint8_t* l) {
  __builtin_amdgcn_global_load_lds((const __attribute__((address_space(1))) void*)g,
                                   (__attribute__((address_space(3))) void*)l, 16, 0, 0);
}

// T1: XCD-chunked blockIdx swizzle (grid divisible by 8 — all ours are).
__device__ __forceinline__ int xswz(int grid) {
  int cpx = grid >> 3;
  return (blockIdx.x & 7) * cpx + (blockIdx.x >> 3);
}

// ---- adj fp32 -> fp8, plus rdenom = 1/(rowsum+1). One wave per row of 512.
__global__ void k_cvt_adj(const float* __restrict__ adj, uint8_t* __restrict__ adjf8,
                          float* __restrict__ rden) {
  int row = blockIdx.x * 4 + (threadIdx.x >> 6);
  int lane = threadIdx.x & 63;
  const float* src = adj + (size_t)row * SS;
  vfloat4 a = *(const vfloat4*)(src + lane * 8);
  vfloat4 b = *(const vfloat4*)(src + lane * 8 + 4);
  uint32_t w0 = 0, w1 = 0;
  w0 = __builtin_amdgcn_cvt_pk_fp8_f32(a[0], a[1], w0, false);
  w0 = __builtin_amdgcn_cvt_pk_fp8_f32(a[2], a[3], w0, true);
  w1 = __builtin_amdgcn_cvt_pk_fp8_f32(b[0], b[1], w1, false);
  w1 = __builtin_amdgcn_cvt_pk_fp8_f32(b[2], b[3], w1, true);
  uint2v o; o[0] = w0; o[1] = w1;
  *(uint2v*)(adjf8 + (size_t)row * SS + lane * 8) = o;
  float s = a[0]+a[1]+a[2]+a[3]+b[0]+b[1]+b[2]+b[3];
  #pragma unroll
  for (int off = 32; off > 0; off >>= 1) s += __shfl_xor(s, off);
  if (lane == 0) rden[row] = 1.0f / (s + 1.0f);
}

// ---- W_gcn fp32 -> bf16 (gemmB); W_out fp32 -> fp8 x64 (gemmF).
__global__ void k_cvt_w(const float* __restrict__ wg, const float* __restrict__ wo,
                        short* __restrict__ wgb, uint8_t* __restrict__ wob) {
  size_t i = ((size_t)blockIdx.x * 256 + threadIdx.x) * 8;
  vfloat4 a = *(const vfloat4*)(wg + i);
  vfloat4 b = *(const vfloat4*)(wg + i + 4);
  bf16x8 ow;
  ow[0]=f2b(a[0]); ow[1]=f2b(a[1]); ow[2]=f2b(a[2]); ow[3]=f2b(a[3]);
  ow[4]=f2b(b[0]); ow[5]=f2b(b[1]); ow[6]=f2b(b[2]); ow[7]=f2b(b[3]);
  *(bf16x8*)(wgb + i) = ow;
  a = *(const vfloat4*)(wo + i);
  b = *(const vfloat4*)(wo + i + 4);
  uint32_t w0 = 0, w1 = 0;
  w0 = __builtin_amdgcn_cvt_pk_fp8_f32(a[0]*64.f, a[1]*64.f, w0, false);
  w0 = __builtin_amdgcn_cvt_pk_fp8_f32(a[2]*64.f, a[3]*64.f, w0, true);
  w1 = __builtin_amdgcn_cvt_pk_fp8_f32(b[0]*64.f, b[1]*64.f, w1, false);
  w1 = __builtin_amdgcn_cvt_pk_fp8_f32(b[2]*64.f, b[3]*64.f, w1, true);
  uint2v o; o[0] = w0; o[1] = w1;
  *(uint2v*)(wob + i) = o;
}

// ---- gcn_inputs [B][S][D] fp32 -> X0T fp8 [B][D][S] + x0b bf16 [B][S][D]
__global__ void k_t_x0(const float* __restrict__ x, uint8_t* __restrict__ xt,
                       short* __restrict__ x0b) {
  __shared__ short t[64][72];
  int bid = blockIdx.x;            // BB*64
  int b = bid >> 6, q = bid & 63;
  int s0 = (q >> 3) * 64, d0 = (q & 7) * 64;
  int tid = threadIdx.x;
  int r = tid >> 4, c4 = (tid & 15) * 4;
  const float* src = x + ((size_t)b * SS + s0) * DD + d0;
  #pragma unroll
  for (int rr = 0; rr < 64; rr += 16) {
    vfloat4 v = *(const vfloat4*)(src + (size_t)(r + rr) * DD + c4);
    shortx4 o4;
    o4[0] = f2b(v[0]); o4[1] = f2b(v[1]); o4[2] = f2b(v[2]); o4[3] = f2b(v[3]);
    t[r+rr][c4+0] = o4[0]; t[r+rr][c4+1] = o4[1];
    t[r+rr][c4+2] = o4[2]; t[r+rr][c4+3] = o4[3];
    *(shortx4*)(x0b + ((size_t)b * SS + s0 + r + rr) * DD + d0 + c4) = o4;
  }
  __syncthreads();
  int dloc = tid >> 3, s8 = (tid & 7) * 8;
  uint8_t* dst = xt + (size_t)b * DD * SS + s0;
  #pragma unroll
  for (int dd = 0; dd < 64; dd += 32) {
    float f[8];
    #pragma unroll
    for (int j = 0; j < 8; j++) f[j] = b2f(t[s8 + j][dloc + dd]);
    uint32_t w0 = 0, w1 = 0;
    w0 = __builtin_amdgcn_cvt_pk_fp8_f32(f[0], f[1], w0, false);
    w0 = __builtin_amdgcn_cvt_pk_fp8_f32(f[2], f[3], w0, true);
    w1 = __builtin_amdgcn_cvt_pk_fp8_f32(f[4], f[5], w1, false);
    w1 = __builtin_amdgcn_cvt_pk_fp8_f32(f[6], f[7], w1, true);
    uint2v o; o[0] = w0; o[1] = w1;
    *(uint2v*)(dst + (size_t)(d0 + dloc + dd) * SS + s8) = o;
  }
}

// ============================ fp8 GEMM core ============================
// C(128x128) = A(128xK fp8, lda bytes) * B'(128xK fp8, ldb bytes)^T.
// 4 waves, 64x64 each; mfma_f32_16x16x32_fp8_fp8 (8 fp8/lane per operand).
// LDS: 4 bufs x (A 4096B | B 4096B) = 32KB -> 4-5 blocks/CU; lead-3,
// steady wait vmcnt(4) (2 loads/stage, 6 in flight).
// Tile [128 rows][32B]; 8B slot s of row r holds global slot s^(2*((r>>2)&1))
// (16B-pair involution, preserves gld16 contiguity; <=2-way banks on read).
__device__ __forceinline__ void compute32f8(const uint8_t* As, const uint8_t* Bs,
                                            int wr, int wc, int lrow, int kslot,
                                            f32x4 acc[4][4]) {
  long af[4], bv[4];
  #pragma unroll
  for (int m = 0; m < 4; m++)
    af[m] = *(const long*)(As + (wr*64 + m*16 + lrow) * 32 + kslot);
  #pragma unroll
  for (int n = 0; n < 4; n++)
    bv[n] = *(const long*)(Bs + (wc*64 + n*16 + lrow) * 32 + kslot);
  #pragma unroll
  for (int m = 0; m < 4; m++)
    #pragma unroll
    for (int n = 0; n < 4; n++)
      acc[m][n] = __builtin_amdgcn_mfma_f32_16x16x32_fp8_fp8(af[m], bv[n], acc[m][n], 0, 0, 0);
}

__device__ __forceinline__ void gemmf8(const uint8_t* __restrict__ A, int lda,
                                       const uint8_t* __restrict__ Bm, int ldb,
                                       int K, uint8_t* lds, f32x4 acc[4][4]) {
  int tid = threadIdx.x;
  int lane = tid & 63, wid = tid >> 6;
  int wr = wid >> 1, wc = wid & 1;
  int lrow = lane & 15;
  int kslot = (((lane >> 4) ^ ((((lane & 15) >> 2) & 1) << 1)) << 3);
  int row = tid >> 1, h = tid & 1;
  int gc = ((h ^ ((row >> 2) & 1)) << 4);
  const uint8_t* ga = A + (size_t)row * lda + gc;
  const uint8_t* gb = Bm + (size_t)row * ldb + gc;

  #define STG(BUF, kt) do { \
    gld16b(ga + (size_t)(kt) * 32, (BUF) + tid * 16); \
    gld16b(gb + (size_t)(kt) * 32, (BUF) + 4096 + tid * 16); } while (0)
  #define STEPW(VM) do { \
    asm volatile("s_waitcnt vmcnt(" #VM ")" ::: "memory"); \
    __builtin_amdgcn_s_barrier(); \
    __builtin_amdgcn_sched_barrier(0); } while (0)
  #define ROT4 do { uint8_t* t_ = p0; p0 = p1; p1 = p2; p2 = p3; p3 = t_; } while (0)

  uint8_t* p0 = lds;
  uint8_t* p1 = lds + 8192;
  uint8_t* p2 = lds + 16384;
  uint8_t* p3 = lds + 24576;
  int NT = K / 32;                 // 16 (gemmA) or 24 (gemmF)
  STG(p0, 0); STG(p1, 1); STG(p2, 2);
  for (int t = 0; t < NT - 3; t++) {
    STEPW(4);
    STG(p3, t + 3);
    compute32f8(p0, p0 + 4096, wr, wc, lrow, kslot, acc);
    ROT4;
  }
  STEPW(4); compute32f8(p0, p0 + 4096, wr, wc, lrow, kslot, acc); ROT4;
  STEPW(2); compute32f8(p0, p0 + 4096, wr, wc, lrow, kslot, acc); ROT4;
  STEPW(0); compute32f8(p0, p0 + 4096, wr, wc, lrow, kslot, acc);
  #undef STG
  #undef STEPW
  #undef ROT4
}

// ============================ bf16 GEMM core (R5, proven) ============================
__device__ __forceinline__ void compute32(const short* As, const short* Bs,
                                          int wr, int wc, int lrow, int kgs,
                                          f32x4 acc[4][4]) {
  bf16x8 af[4], bv[4];
  #pragma unroll
  for (int m = 0; m < 4; m++)
    af[m] = *(const bf16x8*)(As + (wr*64 + m*16 + lrow) * 32 + kgs);
  #pragma unroll
  for (int n = 0; n < 4; n++)
    bv[n] = *(const bf16x8*)(Bs + (wc*64 + n*16 + lrow) * 32 + kgs);
  #pragma unroll
  for (int m = 0; m < 4; m++)
    #pragma unroll
    for (int n = 0; n < 4; n++)
      acc[m][n] = __builtin_amdgcn_mfma_f32_16x16x32_bf16(af[m], bv[n], acc[m][n], 0, 0, 0);
}

__device__ __forceinline__ void gemm2ph(const short* __restrict__ A, int lda,
                                        const short* __restrict__ Bm, int ldb,
                                        int K, short* lds, f32x4 acc[4][4]) {
  int tid = threadIdx.x;
  int lane = tid & 63, wid = tid >> 6;
  int wr = wid >> 1, wc = wid & 1;
  int lrow = lane & 15;
  int kgs = (((lane >> 4) ^ ((lane >> 1) & 3)) << 3);
  int gcol = (((tid & 3) ^ ((tid >> 3) & 3)) << 3);
  const short* ga = A + (size_t)(tid >> 2) * lda + gcol;
  const short* gb = Bm + (size_t)(tid >> 2) * ldb + gcol;

  #define STAGE(BUF, k0) do { \
    short* as_ = (BUF); short* bs_ = (BUF) + 4096; \
    gld16(ga + (k0), as_ + tid*8); \
    gld16(ga + (k0) + (size_t)64 * lda, as_ + 2048 + tid*8); \
    gld16(gb + (k0), bs_ + tid*8); \
    gld16(gb + (k0) + (size_t)64 * ldb, bs_ + 2048 + tid*8); \
  } while (0)

  short* b0 = lds;
  short* b1 = lds + 8192;
  short* b2 = lds + 16384;
  int NT = K / 32;
  STAGE(b0, 0);
  STAGE(b1, 32);
  for (int t = 0; t < NT - 1; t++) {
    asm volatile("s_waitcnt vmcnt(4)" ::: "memory");
    __builtin_amdgcn_s_barrier();
    __builtin_amdgcn_sched_barrier(0);
    if (t + 2 < NT) STAGE(b2, (t + 2) * 32);
    compute32(b0, b0 + 4096, wr, wc, lrow, kgs, acc);
    short* tmp = b0; b0 = b1; b1 = b2; b2 = tmp;
  }
  asm volatile("s_waitcnt vmcnt(0)" ::: "memory");
  __builtin_amdgcn_s_barrier();
  __builtin_amdgcn_sched_barrier(0);
  compute32(b0, b0 + 4096, wr, wc, lrow, kgs, acc);
  #undef STAGE
}

// ---- kA (fp8): AxpX[hb] = adj_hb @ X_{h,layer} + X   (bf16 out)
__global__ __launch_bounds__(256, 4) void k_gemmA(
    const uint8_t* __restrict__ adjf8, const uint8_t* __restrict__ btp,
    const short* __restrict__ x0b, const uint8_t* __restrict__ finb,
    int layer, short* __restrict__ axpx) {
  __shared__ uint8_t lds[32768];
  int bx = xswz(HH*BB*16);
  int q = bx & 15;
  int g = bx >> 4;                 // b-major grouping: g = b*3 + h
  int b = g / 3, h = g - b * 3;
  int hb = h * BB + b;
  int tr = q >> 2, tc = q & 3;
  const uint8_t* A = adjf8 + (size_t)hb * SS * SS + (size_t)(tr * 128) * SS;
  const uint8_t* Bm = (layer == 0)
      ? btp + (size_t)b * DD * SS + (size_t)(tc * 128) * SS
      : btp + (size_t)hb * DD * SS + (size_t)(tc * 128) * SS;
  f32x4 acc[4][4];
  #pragma unroll
  for (int m = 0; m < 4; m++)
    #pragma unroll
    for (int n = 0; n < 4; n++) acc[m][n] = (f32x4){0.f, 0.f, 0.f, 0.f};
  gemmf8(A, SS, Bm, SS, SS, lds, acc);
  int lane = threadIdx.x & 63, wid = threadIdx.x >> 6;
  int wr = wid >> 1, wc = wid & 1;
  int r4 = (lane >> 4) * 4, cn = lane & 15;
  short* outp = axpx + (size_t)hb * SS * DD;
  #pragma unroll
  for (int m = 0; m < 4; m++) {
    #pragma unroll
    for (int n = 0; n < 4; n++) {
      #pragma unroll
      for (int r = 0; r < 4; r++) {
        int s = tr*128 + wr*64 + m*16 + r4 + r;
        int d = tc*128 + wc*64 + n*16 + cn;
        float v;
        if (layer == 0)
          v = acc[m][n][r] + b2f(x0b[((size_t)b * SS + s) * DD + d]);
        else
          v = (acc[m][n][r] + c8(finb[((size_t)b * SS + s) * FF + (size_t)(h * LL) * DD + d]))
              * 0.015625f;   // yt,finb carry x64 scale
        outp[(size_t)s * DD + d] = f2b(v);
      }
    }
  }
}

// ---- kB (bf16): Y = relu((AxpX @ W^T + 2b) * rdenom) -> finb fp8(x64);
//      layer 0 also writes yt fp8(x64) transposed.
__global__ __launch_bounds__(256, 3) void k_gemmB(
    const short* __restrict__ axpx, const short* __restrict__ wgb,
    const float* __restrict__ bg, const float* __restrict__ rden,
    int layer, uint8_t* __restrict__ finb, uint8_t* __restrict__ yt) {
  __shared__ short lds[24576];
  int bx = xswz(HH*BB*16);
  int hb = bx >> 4, q = bx & 15;
  int h = hb / BB, b = hb % BB;
  int tr = q >> 2, tc = q & 3;
  int idx = h * LL + layer;
  const short* A = axpx + (size_t)hb * SS * DD + (size_t)(tr * 128) * DD;
  const short* Bm = wgb + (size_t)idx * DD * DD + (size_t)(tc * 128) * DD;
  f32x4 acc[4][4];
  #pragma unroll
  for (int m = 0; m < 4; m++)
    #pragma unroll
    for (int n = 0; n < 4; n++) acc[m][n] = (f32x4){0.f, 0.f, 0.f, 0.f};
  gemm2ph(A, DD, Bm, DD, DD, lds, acc);
  int lane = threadIdx.x & 63, wid = threadIdx.x >> 6;
  int wr = wid >> 1, wc = wid & 1;
  int r4 = (lane >> 4) * 4, cn = lane & 15;
  #pragma unroll
  for (int m = 0; m < 4; m++) {
    #pragma unroll
    for (int n = 0; n < 4; n++) {
      int sb = tr*128 + wr*64 + m*16 + r4;
      int e = tc*128 + wc*64 + n*16 + cn;
      float vv[4];
      #pragma unroll
      for (int r = 0; r < 4; r++) {
        float v = (acc[m][n][r] + 2.0f * bg[(size_t)idx * DD + e])
                  * rden[(size_t)hb * SS + sb + r];
        vv[r] = fmaxf(v, 0.0f) * 64.0f;
      }
      uint32_t pk4 = 0;
      pk4 = __builtin_amdgcn_cvt_pk_fp8_f32(vv[0], vv[1], pk4, false);
      pk4 = __builtin_amdgcn_cvt_pk_fp8_f32(vv[2], vv[3], pk4, true);
      #pragma unroll
      for (int r = 0; r < 4; r++)
        finb[((size_t)b * SS + sb + r) * FF + (size_t)idx * DD + e] =
            (uint8_t)(pk4 >> (8 * r));
      if (layer == 0)
        *(uint32_t*)(yt + (size_t)hb * DD * SS + (size_t)e * SS + sb) = pk4;
    }
  }
}

// ---- kF (fp8, split-K=4): part[ks] = finb[:, ks*768+..] @ wob[:, same]^T / 4096
__global__ __launch_bounds__(256, 4) void k_gemmF(
    const uint8_t* __restrict__ finb, const uint8_t* __restrict__ wob,
    short* __restrict__ part) {
  __shared__ uint8_t lds[32768];
  int bx = xswz(BB*16*4);          // 1024 blocks
  int ks = bx >> 8;                // 0..3
  int q = bx & 255;
  int tr = q >> 2, tc = q & 3;     // tr 0..63, tc 0..3
  const uint8_t* A = finb + (size_t)(tr * 128) * FF + ks * 768;
  const uint8_t* Bm = wob + (size_t)(tc * 128) * FF + ks * 768;
  f32x4 acc[4][4];
  #pragma unroll
  for (int m = 0; m < 4; m++)
    #pragma unroll
    for (int n = 0; n < 4; n++) acc[m][n] = (f32x4){0.f, 0.f, 0.f, 0.f};
  gemmf8(A, FF, Bm, FF, 768, lds, acc);
  int lane = threadIdx.x & 63, wid = threadIdx.x >> 6;
  int wr = wid >> 1, wc = wid & 1;
  int r4 = (lane >> 4) * 4, cn = lane & 15;
  short* op = part + (size_t)ks * ((size_t)BB*SS*DD);
  #pragma unroll
  for (int m = 0; m < 4; m++) {
    #pragma unroll
    for (int n = 0; n < 4; n++) {
      #pragma unroll
      for (int r = 0; r < 4; r++) {
        int row = tr*128 + wr*64 + m*16 + r4 + r;
        int d = tc*128 + wc*64 + n*16 + cn;
        op[(size_t)row * DD + d] = f2b(acc[m][n][r] * (1.0f / 4096.0f));
      }
    }
  }
}

// ---- reduce: out = x0 + b_out + sum_ks part[ks]   (bf16 parts, 8/thread)
__global__ void k_redF(const short* __restrict__ part, const float* __restrict__ x0f,
                       const float* __restrict__ bo, float* __restrict__ out) {
  const size_t PSZ = (size_t)BB * SS * DD;          // 4,194,304
  size_t i = ((size_t)blockIdx.x * 256 + threadIdx.x) * 8;
  if (i >= PSZ) return;
  int d = (int)(i & (DD - 1));
  bf16x8 q0 = *(const bf16x8*)(part + i);
  bf16x8 q1 = *(const bf16x8*)(part + PSZ + i);
  bf16x8 q2 = *(const bf16x8*)(part + 2*PSZ + i);
  bf16x8 q3 = *(const bf16x8*)(part + 3*PSZ + i);
  vfloat4 xa = *(const vfloat4*)(x0f + i);
  vfloat4 xb = *(const vfloat4*)(x0f + i + 4);
  vfloat4 ba = *(const vfloat4*)(bo + d);
  vfloat4 bb = *(const vfloat4*)(bo + d + 4);
  vfloat4 oa, ob;
  #pragma unroll
  for (int j = 0; j < 4; j++) {
    oa[j] = b2f(q0[j]) + b2f(q1[j]) + b2f(q2[j]) + b2f(q3[j]) + xa[j] + ba[j];
    ob[j] = b2f(q0[j+4]) + b2f(q1[j+4]) + b2f(q2[j+4]) + b2f(q3[j+4]) + xb[j] + bb[j];
  }
  *(vfloat4*)(out + i) = oa;
  *(vfloat4*)(out + i + 4) = ob;
}

extern "C" void kernel_launch(void* const* d_in, const int* in_sizes, int n_in,
                              void* d_out, int out_size, void* d_ws, size_t ws_size,
                              hipStream_t stream) {
  const float* adj = (const float*)d_in[0];
  const float* x0  = (const float*)d_in[1];
  // d_in[2], d_in[3]: mask / domain_mask — unused by the reference forward.
  const float* wg  = (const float*)d_in[4];
  const float* bg  = (const float*)d_in[5];
  const float* wo  = (const float*)d_in[6];
  const float* bo  = (const float*)d_in[7];
  float* out = (float*)d_out;

  char* p = (char*)d_ws;
  uint8_t* adjf8 = (uint8_t*)p; p += (size_t)HH*BB*SS*SS;   // 12,582,912
  uint8_t* x0t   = (uint8_t*)p; p += (size_t)BB*DD*SS;      //  4,194,304
  uint8_t* yt    = (uint8_t*)p; p += (size_t)HH*BB*DD*SS;   // 12,582,912
  short*   axpx  = (short*)p;   p += (size_t)HH*BB*SS*DD*2; // 25,165,824
  uint8_t* finb  = (uint8_t*)p; p += (size_t)BB*SS*FF;      // 25,165,824
  short*   wgb   = (short*)p;   p += (size_t)HH*LL*DD*DD*2; //  3,145,728
  uint8_t* wob   = (uint8_t*)p; p += (size_t)DD*FF;         //  1,572,864
  float*   rden  = (float*)p;   p += (size_t)HH*BB*SS*4;    //     98,304
  short*   x0b   = (short*)p;   p += (size_t)BB*SS*DD*2;    // 16,777,216
  // total ~96.6 MiB. split-K=4 bf16 parts (33.5 MB) overlay adjf8..axpx-head
  // (all dead by gemmF time).
  short* part = (short*)d_ws;

  k_cvt_adj<<<HH*BB*SS/4, 256, 0, stream>>>(adj, adjf8, rden);
  k_cvt_w<<<768, 256, 0, stream>>>(wg, wo, wgb, wob);
  k_t_x0<<<BB*64, 256, 0, stream>>>(x0, x0t, x0b);

  // layer 0
  k_gemmA<<<HH*BB*16, 256, 0, stream>>>(adjf8, x0t, x0b, finb, 0, axpx);
  k_gemmB<<<HH*BB*16, 256, 0, stream>>>(axpx, wgb, bg, rden, 0, finb, yt);
  // layer 1 (gemmB layer-0 epilogue wrote yt = transposed fp8 x64 outputs)
  k_gemmA<<<HH*BB*16, 256, 0, stream>>>(adjf8, yt, x0b, finb, 1, axpx);
  k_gemmB<<<HH*BB*16, 256, 0, stream>>>(axpx, wgb, bg, rden, 1, finb, yt);
  // output projection (fp8, split-K=4) + fused reduce w/ bias + residual
  k_gemmF<<<BB*16*4, 256, 0, stream>>>(finb, wob, part);
  k_redF<<<2048, 256, 0, stream>>>(part, x0, bo, out);
}

// Round 9
// 168.428 us; speedup vs baseline: 1.3150x; 1.0340x over previous
//
#include <hip/hip_runtime.h>
#include <hip/hip_bf16.h>
#include <stdint.h>

// MultiGraphConvLayer: H=3 heads, L=2 layers, B=16, S=512, D=512.
// Round 9: full-fp8 GEMM pipeline. adj/x0t/yt/finb/wob/wgb/axpx all fp8
// (scales: y,w x64; axpx x2), every GEMM on the fp8 core (4x8KB bufs,
// lead-3, vmcnt(4)); scales undone in fp32 epilogues.

#define HH 3
#define LL 2
#define BB 16
#define SS 512
#define DD 512
#define FF 3072  // HH*LL*DD

typedef __attribute__((ext_vector_type(8))) short bf16x8;
typedef __attribute__((ext_vector_type(4))) float f32x4;
typedef __attribute__((ext_vector_type(4))) float vfloat4;
typedef __attribute__((ext_vector_type(4))) short shortx4;
typedef __attribute__((ext_vector_type(2))) unsigned int uint2v;

__device__ __forceinline__ short f2b(float x) {
  union { float f; uint32_t u; } v; v.f = x;
  return (short)((v.u + 0x7FFFu + ((v.u >> 16) & 1u)) >> 16);
}
__device__ __forceinline__ float b2f(short s) {
  union { uint32_t u; float f; } v; v.u = ((uint32_t)(uint16_t)s) << 16;
  return v.f;
}
__device__ __forceinline__ float c8(uint8_t b) {
  return __builtin_amdgcn_cvt_f32_fp8((int)b, 0);
}

__device__ __forceinline__ void gld16b(const uint8_t* g, uint8_t* l) {
  __builtin_amdgcn_global_load_lds((const __attribute__((address_space(1))) void*)g,
                                   (__attribute__((address_space(3))) void*)l, 16, 0, 0);
}

// T1: XCD-chunked blockIdx swizzle (grid divisible by 8 — all ours are).
__device__ __forceinline__ int xswz(int grid) {
  int cpx = grid >> 3;
  return (blockIdx.x & 7) * cpx + (blockIdx.x >> 3);
}

// ---- adj fp32 -> fp8, plus rdenom = 1/(rowsum+1). One wave per row of 512.
__global__ void k_cvt_adj(const float* __restrict__ adj, uint8_t* __restrict__ adjf8,
                          float* __restrict__ rden) {
  int row = blockIdx.x * 4 + (threadIdx.x >> 6);
  int lane = threadIdx.x & 63;
  const float* src = adj + (size_t)row * SS;
  vfloat4 a = *(const vfloat4*)(src + lane * 8);
  vfloat4 b = *(const vfloat4*)(src + lane * 8 + 4);
  uint32_t w0 = 0, w1 = 0;
  w0 = __builtin_amdgcn_cvt_pk_fp8_f32(a[0], a[1], w0, false);
  w0 = __builtin_amdgcn_cvt_pk_fp8_f32(a[2], a[3], w0, true);
  w1 = __builtin_amdgcn_cvt_pk_fp8_f32(b[0], b[1], w1, false);
  w1 = __builtin_amdgcn_cvt_pk_fp8_f32(b[2], b[3], w1, true);
  uint2v o; o[0] = w0; o[1] = w1;
  *(uint2v*)(adjf8 + (size_t)row * SS + lane * 8) = o;
  float s = a[0]+a[1]+a[2]+a[3]+b[0]+b[1]+b[2]+b[3];
  #pragma unroll
  for (int off = 32; off > 0; off >>= 1) s += __shfl_xor(s, off);
  if (lane == 0) rden[row] = 1.0f / (s + 1.0f);
}

// ---- W_gcn fp32 -> fp8 x64; W_out fp32 -> fp8 x64.
__global__ void k_cvt_w(const float* __restrict__ wg, const float* __restrict__ wo,
                        uint8_t* __restrict__ wgb, uint8_t* __restrict__ wob) {
  size_t i = ((size_t)blockIdx.x * 256 + threadIdx.x) * 8;
  vfloat4 a = *(const vfloat4*)(wg + i);
  vfloat4 b = *(const vfloat4*)(wg + i + 4);
  uint32_t w0 = 0, w1 = 0;
  w0 = __builtin_amdgcn_cvt_pk_fp8_f32(a[0]*64.f, a[1]*64.f, w0, false);
  w0 = __builtin_amdgcn_cvt_pk_fp8_f32(a[2]*64.f, a[3]*64.f, w0, true);
  w1 = __builtin_amdgcn_cvt_pk_fp8_f32(b[0]*64.f, b[1]*64.f, w1, false);
  w1 = __builtin_amdgcn_cvt_pk_fp8_f32(b[2]*64.f, b[3]*64.f, w1, true);
  uint2v o; o[0] = w0; o[1] = w1;
  *(uint2v*)(wgb + i) = o;
  a = *(const vfloat4*)(wo + i);
  b = *(const vfloat4*)(wo + i + 4);
  w0 = 0; w1 = 0;
  w0 = __builtin_amdgcn_cvt_pk_fp8_f32(a[0]*64.f, a[1]*64.f, w0, false);
  w0 = __builtin_amdgcn_cvt_pk_fp8_f32(a[2]*64.f, a[3]*64.f, w0, true);
  w1 = __builtin_amdgcn_cvt_pk_fp8_f32(b[0]*64.f, b[1]*64.f, w1, false);
  w1 = __builtin_amdgcn_cvt_pk_fp8_f32(b[2]*64.f, b[3]*64.f, w1, true);
  o[0] = w0; o[1] = w1;
  *(uint2v*)(wob + i) = o;
}

// ---- gcn_inputs [B][S][D] fp32 -> X0T fp8 [B][D][S] + x0b bf16 [B][S][D]
__global__ void k_t_x0(const float* __restrict__ x, uint8_t* __restrict__ xt,
                       short* __restrict__ x0b) {
  __shared__ short t[64][72];
  int bid = blockIdx.x;            // BB*64
  int b = bid >> 6, q = bid & 63;
  int s0 = (q >> 3) * 64, d0 = (q & 7) * 64;
  int tid = threadIdx.x;
  int r = tid >> 4, c4 = (tid & 15) * 4;
  const float* src = x + ((size_t)b * SS + s0) * DD + d0;
  #pragma unroll
  for (int rr = 0; rr < 64; rr += 16) {
    vfloat4 v = *(const vfloat4*)(src + (size_t)(r + rr) * DD + c4);
    shortx4 o4;
    o4[0] = f2b(v[0]); o4[1] = f2b(v[1]); o4[2] = f2b(v[2]); o4[3] = f2b(v[3]);
    t[r+rr][c4+0] = o4[0]; t[r+rr][c4+1] = o4[1];
    t[r+rr][c4+2] = o4[2]; t[r+rr][c4+3] = o4[3];
    *(shortx4*)(x0b + ((size_t)b * SS + s0 + r + rr) * DD + d0 + c4) = o4;
  }
  __syncthreads();
  int dloc = tid >> 3, s8 = (tid & 7) * 8;
  uint8_t* dst = xt + (size_t)b * DD * SS + s0;
  #pragma unroll
  for (int dd = 0; dd < 64; dd += 32) {
    float f[8];
    #pragma unroll
    for (int j = 0; j < 8; j++) f[j] = b2f(t[s8 + j][dloc + dd]);
    uint32_t w0 = 0, w1 = 0;
    w0 = __builtin_amdgcn_cvt_pk_fp8_f32(f[0], f[1], w0, false);
    w0 = __builtin_amdgcn_cvt_pk_fp8_f32(f[2], f[3], w0, true);
    w1 = __builtin_amdgcn_cvt_pk_fp8_f32(f[4], f[5], w1, false);
    w1 = __builtin_amdgcn_cvt_pk_fp8_f32(f[6], f[7], w1, true);
    uint2v o; o[0] = w0; o[1] = w1;
    *(uint2v*)(dst + (size_t)(d0 + dloc + dd) * SS + s8) = o;
  }
}

// ============================ fp8 GEMM core (R8, proven) ============================
// C(128x128) = A(128xK fp8, lda bytes) * B'(128xK fp8, ldb bytes)^T.
// 4 waves, 64x64 each; mfma_f32_16x16x32_fp8_fp8; LDS 4 bufs x 8KB = 32KB;
// lead-3, steady vmcnt(4). 16B-pair XOR involution swizzle on both sides.
__device__ __forceinline__ void compute32f8(const uint8_t* As, const uint8_t* Bs,
                                            int wr, int wc, int lrow, int kslot,
                                            f32x4 acc[4][4]) {
  long af[4], bv[4];
  #pragma unroll
  for (int m = 0; m < 4; m++)
    af[m] = *(const long*)(As + (wr*64 + m*16 + lrow) * 32 + kslot);
  #pragma unroll
  for (int n = 0; n < 4; n++)
    bv[n] = *(const long*)(Bs + (wc*64 + n*16 + lrow) * 32 + kslot);
  #pragma unroll
  for (int m = 0; m < 4; m++)
    #pragma unroll
    for (int n = 0; n < 4; n++)
      acc[m][n] = __builtin_amdgcn_mfma_f32_16x16x32_fp8_fp8(af[m], bv[n], acc[m][n], 0, 0, 0);
}

__device__ __forceinline__ void gemmf8(const uint8_t* __restrict__ A, int lda,
                                       const uint8_t* __restrict__ Bm, int ldb,
                                       int K, uint8_t* lds, f32x4 acc[4][4]) {
  int tid = threadIdx.x;
  int lane = tid & 63, wid = tid >> 6;
  int wr = wid >> 1, wc = wid & 1;
  int lrow = lane & 15;
  int kslot = (((lane >> 4) ^ ((((lane & 15) >> 2) & 1) << 1)) << 3);
  int row = tid >> 1, h = tid & 1;
  int gc = ((h ^ ((row >> 2) & 1)) << 4);
  const uint8_t* ga = A + (size_t)row * lda + gc;
  const uint8_t* gb = Bm + (size_t)row * ldb + gc;

  #define STG(BUF, kt) do { \
    gld16b(ga + (size_t)(kt) * 32, (BUF) + tid * 16); \
    gld16b(gb + (size_t)(kt) * 32, (BUF) + 4096 + tid * 16); } while (0)
  #define STEPW(VM) do { \
    asm volatile("s_waitcnt vmcnt(" #VM ")" ::: "memory"); \
    __builtin_amdgcn_s_barrier(); \
    __builtin_amdgcn_sched_barrier(0); } while (0)
  #define ROT4 do { uint8_t* t_ = p0; p0 = p1; p1 = p2; p2 = p3; p3 = t_; } while (0)

  uint8_t* p0 = lds;
  uint8_t* p1 = lds + 8192;
  uint8_t* p2 = lds + 16384;
  uint8_t* p3 = lds + 24576;
  int NT = K / 32;                 // 16 (gemmA/B) or 24 (gemmF)
  STG(p0, 0); STG(p1, 1); STG(p2, 2);
  for (int t = 0; t < NT - 3; t++) {
    STEPW(4);
    STG(p3, t + 3);
    compute32f8(p0, p0 + 4096, wr, wc, lrow, kslot, acc);
    ROT4;
  }
  STEPW(4); compute32f8(p0, p0 + 4096, wr, wc, lrow, kslot, acc); ROT4;
  STEPW(2); compute32f8(p0, p0 + 4096, wr, wc, lrow, kslot, acc); ROT4;
  STEPW(0); compute32f8(p0, p0 + 4096, wr, wc, lrow, kslot, acc);
  #undef STG
  #undef STEPW
  #undef ROT4
}

// ---- kA (fp8): axpx = fp8x2( adj_hb @ X_{h,layer} + X )
__global__ __launch_bounds__(256, 4) void k_gemmA(
    const uint8_t* __restrict__ adjf8, const uint8_t* __restrict__ btp,
    const short* __restrict__ x0b, const uint8_t* __restrict__ finb,
    int layer, uint8_t* __restrict__ axpx) {
  __shared__ uint8_t lds[32768];
  int bx = xswz(HH*BB*16);
  int q = bx & 15;
  int g = bx >> 4;                 // b-major grouping: g = b*3 + h
  int b = g / 3, h = g - b * 3;
  int hb = h * BB + b;
  int tr = q >> 2, tc = q & 3;
  const uint8_t* A = adjf8 + (size_t)hb * SS * SS + (size_t)(tr * 128) * SS;
  const uint8_t* Bm = (layer == 0)
      ? btp + (size_t)b * DD * SS + (size_t)(tc * 128) * SS
      : btp + (size_t)hb * DD * SS + (size_t)(tc * 128) * SS;
  f32x4 acc[4][4];
  #pragma unroll
  for (int m = 0; m < 4; m++)
    #pragma unroll
    for (int n = 0; n < 4; n++) acc[m][n] = (f32x4){0.f, 0.f, 0.f, 0.f};
  gemmf8(A, SS, Bm, SS, SS, lds, acc);
  int lane = threadIdx.x & 63, wid = threadIdx.x >> 6;
  int wr = wid >> 1, wc = wid & 1;
  int r4 = (lane >> 4) * 4, cn = lane & 15;
  uint8_t* outp = axpx + (size_t)hb * SS * DD;
  #pragma unroll
  for (int m = 0; m < 4; m++) {
    #pragma unroll
    for (int n = 0; n < 4; n++) {
      int sb = tr*128 + wr*64 + m*16 + r4;
      int d = tc*128 + wc*64 + n*16 + cn;
      float vv[4];
      #pragma unroll
      for (int r = 0; r < 4; r++) {
        float v;
        if (layer == 0)
          v = acc[m][n][r] + b2f(x0b[((size_t)b * SS + sb + r) * DD + d]);
        else
          v = (acc[m][n][r] + c8(finb[((size_t)b * SS + sb + r) * FF + (size_t)(h * LL) * DD + d]))
              * 0.015625f;   // yt,finb carry x64 scale
        vv[r] = v * 2.0f;    // axpx carries x2 scale
      }
      uint32_t pk4 = 0;
      pk4 = __builtin_amdgcn_cvt_pk_fp8_f32(vv[0], vv[1], pk4, false);
      pk4 = __builtin_amdgcn_cvt_pk_fp8_f32(vv[2], vv[3], pk4, true);
      #pragma unroll
      for (int r = 0; r < 4; r++)
        outp[(size_t)(sb + r) * DD + d] = (uint8_t)(pk4 >> (8 * r));
    }
  }
}

// ---- kB (fp8): Y = relu((AxpX @ W^T + 2b) * rdenom) -> finb fp8(x64);
//      layer 0 also writes yt fp8(x64) transposed.
//      acc = (x2)*(x64) = 128 x true -> /128 in epilogue.
__global__ __launch_bounds__(256, 4) void k_gemmB(
    const uint8_t* __restrict__ axpx, const uint8_t* __restrict__ wgb,
    const float* __restrict__ bg, const float* __restrict__ rden,
    int layer, uint8_t* __restrict__ finb, uint8_t* __restrict__ yt) {
  __shared__ uint8_t lds[32768];
  int bx = xswz(HH*BB*16);
  int hb = bx >> 4, q = bx & 15;
  int h = hb / BB, b = hb % BB;
  int tr = q >> 2, tc = q & 3;
  int idx = h * LL + layer;
  const uint8_t* A = axpx + (size_t)hb * SS * DD + (size_t)(tr * 128) * DD;
  const uint8_t* Bm = wgb + (size_t)idx * DD * DD + (size_t)(tc * 128) * DD;
  f32x4 acc[4][4];
  #pragma unroll
  for (int m = 0; m < 4; m++)
    #pragma unroll
    for (int n = 0; n < 4; n++) acc[m][n] = (f32x4){0.f, 0.f, 0.f, 0.f};
  gemmf8(A, DD, Bm, DD, DD, lds, acc);
  int lane = threadIdx.x & 63, wid = threadIdx.x >> 6;
  int wr = wid >> 1, wc = wid & 1;
  int r4 = (lane >> 4) * 4, cn = lane & 15;
  #pragma unroll
  for (int m = 0; m < 4; m++) {
    #pragma unroll
    for (int n = 0; n < 4; n++) {
      int sb = tr*128 + wr*64 + m*16 + r4;
      int e = tc*128 + wc*64 + n*16 + cn;
      float vv[4];
      #pragma unroll
      for (int r = 0; r < 4; r++) {
        float v = (acc[m][n][r] * 0.0078125f + 2.0f * bg[(size_t)idx * DD + e])
                  * rden[(size_t)hb * SS + sb + r];
        vv[r] = fmaxf(v, 0.0f) * 64.0f;
      }
      uint32_t pk4 = 0;
      pk4 = __builtin_amdgcn_cvt_pk_fp8_f32(vv[0], vv[1], pk4, false);
      pk4 = __builtin_amdgcn_cvt_pk_fp8_f32(vv[2], vv[3], pk4, true);
      #pragma unroll
      for (int r = 0; r < 4; r++)
        finb[((size_t)b * SS + sb + r) * FF + (size_t)idx * DD + e] =
            (uint8_t)(pk4 >> (8 * r));
      if (layer == 0)
        *(uint32_t*)(yt + (size_t)hb * DD * SS + (size_t)e * SS + sb) = pk4;
    }
  }
}

// ---- kF (fp8, split-K=4): part[ks] = finb[:, ks*768+..] @ wob[:, same]^T / 4096
__global__ __launch_bounds__(256, 4) void k_gemmF(
    const uint8_t* __restrict__ finb, const uint8_t* __restrict__ wob,
    short* __restrict__ part) {
  __shared__ uint8_t lds[32768];
  int bx = xswz(BB*16*4);          // 1024 blocks
  int ks = bx >> 8;                // 0..3
  int q = bx & 255;
  int tr = q >> 2, tc = q & 3;     // tr 0..63, tc 0..3
  const uint8_t* A = finb + (size_t)(tr * 128) * FF + ks * 768;
  const uint8_t* Bm = wob + (size_t)(tc * 128) * FF + ks * 768;
  f32x4 acc[4][4];
  #pragma unroll
  for (int m = 0; m < 4; m++)
    #pragma unroll
    for (int n = 0; n < 4; n++) acc[m][n] = (f32x4){0.f, 0.f, 0.f, 0.f};
  gemmf8(A, FF, Bm, FF, 768, lds, acc);
  int lane = threadIdx.x & 63, wid = threadIdx.x >> 6;
  int wr = wid >> 1, wc = wid & 1;
  int r4 = (lane >> 4) * 4, cn = lane & 15;
  short* op = part + (size_t)ks * ((size_t)BB*SS*DD);
  #pragma unroll
  for (int m = 0; m < 4; m++) {
    #pragma unroll
    for (int n = 0; n < 4; n++) {
      #pragma unroll
      for (int r = 0; r < 4; r++) {
        int row = tr*128 + wr*64 + m*16 + r4 + r;
        int d = tc*128 + wc*64 + n*16 + cn;
        op[(size_t)row * DD + d] = f2b(acc[m][n][r] * (1.0f / 4096.0f));
      }
    }
  }
}

// ---- reduce: out = x0 + b_out + sum_ks part[ks]   (bf16 parts, 8/thread)
__global__ void k_redF(const short* __restrict__ part, const float* __restrict__ x0f,
                       const float* __restrict__ bo, float* __restrict__ out) {
  const size_t PSZ = (size_t)BB * SS * DD;          // 4,194,304
  size_t i = ((size_t)blockIdx.x * 256 + threadIdx.x) * 8;
  if (i >= PSZ) return;
  int d = (int)(i & (DD - 1));
  bf16x8 q0 = *(const bf16x8*)(part + i);
  bf16x8 q1 = *(const bf16x8*)(part + PSZ + i);
  bf16x8 q2 = *(const bf16x8*)(part + 2*PSZ + i);
  bf16x8 q3 = *(const bf16x8*)(part + 3*PSZ + i);
  vfloat4 xa = *(const vfloat4*)(x0f + i);
  vfloat4 xb = *(const vfloat4*)(x0f + i + 4);
  vfloat4 ba = *(const vfloat4*)(bo + d);
  vfloat4 bb = *(const vfloat4*)(bo + d + 4);
  vfloat4 oa, ob;
  #pragma unroll
  for (int j = 0; j < 4; j++) {
    oa[j] = b2f(q0[j]) + b2f(q1[j]) + b2f(q2[j]) + b2f(q3[j]) + xa[j] + ba[j];
    ob[j] = b2f(q0[j+4]) + b2f(q1[j+4]) + b2f(q2[j+4]) + b2f(q3[j+4]) + xb[j] + bb[j];
  }
  *(vfloat4*)(out + i) = oa;
  *(vfloat4*)(out + i + 4) = ob;
}

extern "C" void kernel_launch(void* const* d_in, const int* in_sizes, int n_in,
                              void* d_out, int out_size, void* d_ws, size_t ws_size,
                              hipStream_t stream) {
  const float* adj = (const float*)d_in[0];
  const float* x0  = (const float*)d_in[1];
  // d_in[2], d_in[3]: mask / domain_mask — unused by the reference forward.
  const float* wg  = (const float*)d_in[4];
  const float* bg  = (const float*)d_in[5];
  const float* wo  = (const float*)d_in[6];
  const float* bo  = (const float*)d_in[7];
  float* out = (float*)d_out;

  char* p = (char*)d_ws;
  uint8_t* adjf8 = (uint8_t*)p; p += (size_t)HH*BB*SS*SS;   // 12,582,912
  uint8_t* x0t   = (uint8_t*)p; p += (size_t)BB*DD*SS;      //  4,194,304
  uint8_t* yt    = (uint8_t*)p; p += (size_t)HH*BB*DD*SS;   // 12,582,912
  uint8_t* axpx  = (uint8_t*)p; p += (size_t)HH*BB*SS*DD;   // 12,582,912
  uint8_t* finb  = (uint8_t*)p; p += (size_t)BB*SS*FF;      // 25,165,824
  uint8_t* wgb   = (uint8_t*)p; p += (size_t)HH*LL*DD*DD;   //  1,572,864
  uint8_t* wob   = (uint8_t*)p; p += (size_t)DD*FF;         //  1,572,864
  float*   rden  = (float*)p;   p += (size_t)HH*BB*SS*4;    //     98,304
  short*   x0b   = (short*)p;   p += (size_t)BB*SS*DD*2;    //  8,388,608
  // total ~78.7 MiB. split-K=4 bf16 parts (33.5 MB) overlay
  // adjf8+x0t+yt+axpx-head — all dead by gemmF time.
  short* part = (short*)d_ws;

  k_cvt_adj<<<HH*BB*SS/4, 256, 0, stream>>>(adj, adjf8, rden);
  k_cvt_w<<<768, 256, 0, stream>>>(wg, wo, wgb, wob);
  k_t_x0<<<BB*64, 256, 0, stream>>>(x0, x0t, x0b);

  // layer 0
  k_gemmA<<<HH*BB*16, 256, 0, stream>>>(adjf8, x0t, x0b, finb, 0, axpx);
  k_gemmB<<<HH*BB*16, 256, 0, stream>>>(axpx, wgb, bg, rden, 0, finb, yt);
  // layer 1 (gemmB layer-0 epilogue wrote yt = transposed fp8 x64 outputs)
  k_gemmA<<<HH*BB*16, 256, 0, stream>>>(adjf8, yt, x0b, finb, 1, axpx);
  k_gemmB<<<HH*BB*16, 256, 0, stream>>>(axpx, wgb, bg, rden, 1, finb, yt);
  // output projection (fp8, split-K=4) + fused reduce w/ bias + residual
  k_gemmF<<<BB*16*4, 256, 0, stream>>>(finb, wob, part);
  k_redF<<<2048, 256, 0, stream>>>(part, x0, bo, out);
}

// Round 10
// 162.101 us; speedup vs baseline: 1.3663x; 1.0390x over previous
//
#include <hip/hip_runtime.h>
#include <hip/hip_bf16.h>
#include <stdint.h>

// MultiGraphConvLayer: H=3 heads, L=2 layers, B=16, S=512, D=512.
// Round 10: merged prep kernel (adj-cvt + w-cvt + x0-transpose in one
// dispatch, block-range partitioned), gemmF split-K=2, 2-part reduce.
// fp8 GEMM pipeline unchanged from R9 (scales: y,w x64; axpx x2).

#define HH 3
#define LL 2
#define BB 16
#define SS 512
#define DD 512
#define FF 3072  // HH*LL*DD

typedef __attribute__((ext_vector_type(8))) short bf16x8;
typedef __attribute__((ext_vector_type(4))) float f32x4;
typedef __attribute__((ext_vector_type(4))) float vfloat4;
typedef __attribute__((ext_vector_type(4))) short shortx4;
typedef __attribute__((ext_vector_type(2))) unsigned int uint2v;

__device__ __forceinline__ short f2b(float x) {
  union { float f; uint32_t u; } v; v.f = x;
  return (short)((v.u + 0x7FFFu + ((v.u >> 16) & 1u)) >> 16);
}
__device__ __forceinline__ float b2f(short s) {
  union { uint32_t u; float f; } v; v.u = ((uint32_t)(uint16_t)s) << 16;
  return v.f;
}
__device__ __forceinline__ float c8(uint8_t b) {
  return __builtin_amdgcn_cvt_f32_fp8((int)b, 0);
}

__device__ __forceinline__ void gld16b(const uint8_t* g, uint8_t* l) {
  __builtin_amdgcn_global_load_lds((const __attribute__((address_space(1))) void*)g,
                                   (__attribute__((address_space(3))) void*)l, 16, 0, 0);
}

// T1: XCD-chunked blockIdx swizzle (grid divisible by 8 — all ours are).
__device__ __forceinline__ int xswz(int grid) {
  int cpx = grid >> 3;
  return (blockIdx.x & 7) * cpx + (blockIdx.x >> 3);
}

// ---- merged prep: [0,6144) adj->fp8 + rden; [6144,6912) W->fp8 x64;
//      [6912,7936) x0 -> X0T fp8 + x0b bf16.
__global__ void k_prep(const float* __restrict__ adj, uint8_t* __restrict__ adjf8,
                       float* __restrict__ rden,
                       const float* __restrict__ wg, const float* __restrict__ wo,
                       uint8_t* __restrict__ wgb, uint8_t* __restrict__ wob,
                       const float* __restrict__ x, uint8_t* __restrict__ xt,
                       short* __restrict__ x0b) {
  __shared__ short t[64][72];
  int bid = blockIdx.x;
  int tid = threadIdx.x;
  if (bid < 6144) {
    // ---- adj fp32 -> fp8, rdenom. One wave per row of 512.
    int row = bid * 4 + (tid >> 6);
    int lane = tid & 63;
    const float* src = adj + (size_t)row * SS;
    vfloat4 a = *(const vfloat4*)(src + lane * 8);
    vfloat4 b = *(const vfloat4*)(src + lane * 8 + 4);
    uint32_t w0 = 0, w1 = 0;
    w0 = __builtin_amdgcn_cvt_pk_fp8_f32(a[0], a[1], w0, false);
    w0 = __builtin_amdgcn_cvt_pk_fp8_f32(a[2], a[3], w0, true);
    w1 = __builtin_amdgcn_cvt_pk_fp8_f32(b[0], b[1], w1, false);
    w1 = __builtin_amdgcn_cvt_pk_fp8_f32(b[2], b[3], w1, true);
    uint2v o; o[0] = w0; o[1] = w1;
    *(uint2v*)(adjf8 + (size_t)row * SS + lane * 8) = o;
    float s = a[0]+a[1]+a[2]+a[3]+b[0]+b[1]+b[2]+b[3];
    #pragma unroll
    for (int off = 32; off > 0; off >>= 1) s += __shfl_xor(s, off);
    if (lane == 0) rden[row] = 1.0f / (s + 1.0f);
  } else if (bid < 6912) {
    // ---- W_gcn, W_out fp32 -> fp8 x64.
    size_t i = ((size_t)(bid - 6144) * 256 + tid) * 8;
    vfloat4 a = *(const vfloat4*)(wg + i);
    vfloat4 b = *(const vfloat4*)(wg + i + 4);
    uint32_t w0 = 0, w1 = 0;
    w0 = __builtin_amdgcn_cvt_pk_fp8_f32(a[0]*64.f, a[1]*64.f, w0, false);
    w0 = __builtin_amdgcn_cvt_pk_fp8_f32(a[2]*64.f, a[3]*64.f, w0, true);
    w1 = __builtin_amdgcn_cvt_pk_fp8_f32(b[0]*64.f, b[1]*64.f, w1, false);
    w1 = __builtin_amdgcn_cvt_pk_fp8_f32(b[2]*64.f, b[3]*64.f, w1, true);
    uint2v o; o[0] = w0; o[1] = w1;
    *(uint2v*)(wgb + i) = o;
    a = *(const vfloat4*)(wo + i);
    b = *(const vfloat4*)(wo + i + 4);
    w0 = 0; w1 = 0;
    w0 = __builtin_amdgcn_cvt_pk_fp8_f32(a[0]*64.f, a[1]*64.f, w0, false);
    w0 = __builtin_amdgcn_cvt_pk_fp8_f32(a[2]*64.f, a[3]*64.f, w0, true);
    w1 = __builtin_amdgcn_cvt_pk_fp8_f32(b[0]*64.f, b[1]*64.f, w1, false);
    w1 = __builtin_amdgcn_cvt_pk_fp8_f32(b[2]*64.f, b[3]*64.f, w1, true);
    o[0] = w0; o[1] = w1;
    *(uint2v*)(wob + i) = o;
  } else {
    // ---- x0 [B][S][D] fp32 -> X0T fp8 [B][D][S] + x0b bf16 [B][S][D].
    int bid2 = bid - 6912;           // BB*64
    int b = bid2 >> 6, q = bid2 & 63;
    int s0 = (q >> 3) * 64, d0 = (q & 7) * 64;
    int r = tid >> 4, c4 = (tid & 15) * 4;
    const float* src = x + ((size_t)b * SS + s0) * DD + d0;
    #pragma unroll
    for (int rr = 0; rr < 64; rr += 16) {
      vfloat4 v = *(const vfloat4*)(src + (size_t)(r + rr) * DD + c4);
      shortx4 o4;
      o4[0] = f2b(v[0]); o4[1] = f2b(v[1]); o4[2] = f2b(v[2]); o4[3] = f2b(v[3]);
      t[r+rr][c4+0] = o4[0]; t[r+rr][c4+1] = o4[1];
      t[r+rr][c4+2] = o4[2]; t[r+rr][c4+3] = o4[3];
      *(shortx4*)(x0b + ((size_t)b * SS + s0 + r + rr) * DD + d0 + c4) = o4;
    }
    __syncthreads();
    int dloc = tid >> 3, s8 = (tid & 7) * 8;
    uint8_t* dst = xt + (size_t)b * DD * SS + s0;
    #pragma unroll
    for (int dd = 0; dd < 64; dd += 32) {
      float f[8];
      #pragma unroll
      for (int j = 0; j < 8; j++) f[j] = b2f(t[s8 + j][dloc + dd]);
      uint32_t w0 = 0, w1 = 0;
      w0 = __builtin_amdgcn_cvt_pk_fp8_f32(f[0], f[1], w0, false);
      w0 = __builtin_amdgcn_cvt_pk_fp8_f32(f[2], f[3], w0, true);
      w1 = __builtin_amdgcn_cvt_pk_fp8_f32(f[4], f[5], w1, false);
      w1 = __builtin_amdgcn_cvt_pk_fp8_f32(f[6], f[7], w1, true);
      uint2v o; o[0] = w0; o[1] = w1;
      *(uint2v*)(dst + (size_t)(d0 + dloc + dd) * SS + s8) = o;
    }
  }
}

// ============================ fp8 GEMM core (R8, proven) ============================
// C(128x128) = A(128xK fp8, lda bytes) * B'(128xK fp8, ldb bytes)^T.
// 4 waves, 64x64 each; mfma_f32_16x16x32_fp8_fp8; LDS 4 bufs x 8KB = 32KB;
// lead-3, steady vmcnt(4). 16B-pair XOR involution swizzle on both sides.
__device__ __forceinline__ void compute32f8(const uint8_t* As, const uint8_t* Bs,
                                            int wr, int wc, int lrow, int kslot,
                                            f32x4 acc[4][4]) {
  long af[4], bv[4];
  #pragma unroll
  for (int m = 0; m < 4; m++)
    af[m] = *(const long*)(As + (wr*64 + m*16 + lrow) * 32 + kslot);
  #pragma unroll
  for (int n = 0; n < 4; n++)
    bv[n] = *(const long*)(Bs + (wc*64 + n*16 + lrow) * 32 + kslot);
  #pragma unroll
  for (int m = 0; m < 4; m++)
    #pragma unroll
    for (int n = 0; n < 4; n++)
      acc[m][n] = __builtin_amdgcn_mfma_f32_16x16x32_fp8_fp8(af[m], bv[n], acc[m][n], 0, 0, 0);
}

__device__ __forceinline__ void gemmf8(const uint8_t* __restrict__ A, int lda,
                                       const uint8_t* __restrict__ Bm, int ldb,
                                       int K, uint8_t* lds, f32x4 acc[4][4]) {
  int tid = threadIdx.x;
  int lane = tid & 63, wid = tid >> 6;
  int wr = wid >> 1, wc = wid & 1;
  int lrow = lane & 15;
  int kslot = (((lane >> 4) ^ ((((lane & 15) >> 2) & 1) << 1)) << 3);
  int row = tid >> 1, h = tid & 1;
  int gc = ((h ^ ((row >> 2) & 1)) << 4);
  const uint8_t* ga = A + (size_t)row * lda + gc;
  const uint8_t* gb = Bm + (size_t)row * ldb + gc;

  #define STG(BUF, kt) do { \
    gld16b(ga + (size_t)(kt) * 32, (BUF) + tid * 16); \
    gld16b(gb + (size_t)(kt) * 32, (BUF) + 4096 + tid * 16); } while (0)
  #define STEPW(VM) do { \
    asm volatile("s_waitcnt vmcnt(" #VM ")" ::: "memory"); \
    __builtin_amdgcn_s_barrier(); \
    __builtin_amdgcn_sched_barrier(0); } while (0)
  #define ROT4 do { uint8_t* t_ = p0; p0 = p1; p1 = p2; p2 = p3; p3 = t_; } while (0)

  uint8_t* p0 = lds;
  uint8_t* p1 = lds + 8192;
  uint8_t* p2 = lds + 16384;
  uint8_t* p3 = lds + 24576;
  int NT = K / 32;                 // 16 (gemmA/B) or 48 (gemmF)
  STG(p0, 0); STG(p1, 1); STG(p2, 2);
  for (int t = 0; t < NT - 3; t++) {
    STEPW(4);
    STG(p3, t + 3);
    compute32f8(p0, p0 + 4096, wr, wc, lrow, kslot, acc);
    ROT4;
  }
  STEPW(4); compute32f8(p0, p0 + 4096, wr, wc, lrow, kslot, acc); ROT4;
  STEPW(2); compute32f8(p0, p0 + 4096, wr, wc, lrow, kslot, acc); ROT4;
  STEPW(0); compute32f8(p0, p0 + 4096, wr, wc, lrow, kslot, acc);
  #undef STG
  #undef STEPW
  #undef ROT4
}

// ---- kA (fp8): axpx = fp8x2( adj_hb @ X_{h,layer} + X )
__global__ __launch_bounds__(256, 4) void k_gemmA(
    const uint8_t* __restrict__ adjf8, const uint8_t* __restrict__ btp,
    const short* __restrict__ x0b, const uint8_t* __restrict__ finb,
    int layer, uint8_t* __restrict__ axpx) {
  __shared__ uint8_t lds[32768];
  int bx = xswz(HH*BB*16);
  int q = bx & 15;
  int g = bx >> 4;                 // b-major grouping: g = b*3 + h
  int b = g / 3, h = g - b * 3;
  int hb = h * BB + b;
  int tr = q >> 2, tc = q & 3;
  const uint8_t* A = adjf8 + (size_t)hb * SS * SS + (size_t)(tr * 128) * SS;
  const uint8_t* Bm = (layer == 0)
      ? btp + (size_t)b * DD * SS + (size_t)(tc * 128) * SS
      : btp + (size_t)hb * DD * SS + (size_t)(tc * 128) * SS;
  f32x4 acc[4][4];
  #pragma unroll
  for (int m = 0; m < 4; m++)
    #pragma unroll
    for (int n = 0; n < 4; n++) acc[m][n] = (f32x4){0.f, 0.f, 0.f, 0.f};
  gemmf8(A, SS, Bm, SS, SS, lds, acc);
  int lane = threadIdx.x & 63, wid = threadIdx.x >> 6;
  int wr = wid >> 1, wc = wid & 1;
  int r4 = (lane >> 4) * 4, cn = lane & 15;
  uint8_t* outp = axpx + (size_t)hb * SS * DD;
  #pragma unroll
  for (int m = 0; m < 4; m++) {
    #pragma unroll
    for (int n = 0; n < 4; n++) {
      int sb = tr*128 + wr*64 + m*16 + r4;
      int d = tc*128 + wc*64 + n*16 + cn;
      float vv[4];
      #pragma unroll
      for (int r = 0; r < 4; r++) {
        float v;
        if (layer == 0)
          v = acc[m][n][r] + b2f(x0b[((size_t)b * SS + sb + r) * DD + d]);
        else
          v = (acc[m][n][r] + c8(finb[((size_t)b * SS + sb + r) * FF + (size_t)(h * LL) * DD + d]))
              * 0.015625f;   // yt,finb carry x64 scale
        vv[r] = v * 2.0f;    // axpx carries x2 scale
      }
      uint32_t pk4 = 0;
      pk4 = __builtin_amdgcn_cvt_pk_fp8_f32(vv[0], vv[1], pk4, false);
      pk4 = __builtin_amdgcn_cvt_pk_fp8_f32(vv[2], vv[3], pk4, true);
      #pragma unroll
      for (int r = 0; r < 4; r++)
        outp[(size_t)(sb + r) * DD + d] = (uint8_t)(pk4 >> (8 * r));
    }
  }
}

// ---- kB (fp8): Y = relu((AxpX @ W^T + 2b) * rdenom) -> finb fp8(x64);
//      layer 0 also writes yt fp8(x64) transposed. acc scale /128.
__global__ __launch_bounds__(256, 4) void k_gemmB(
    const uint8_t* __restrict__ axpx, const uint8_t* __restrict__ wgb,
    const float* __restrict__ bg, const float* __restrict__ rden,
    int layer, uint8_t* __restrict__ finb, uint8_t* __restrict__ yt) {
  __shared__ uint8_t lds[32768];
  int bx = xswz(HH*BB*16);
  int hb = bx >> 4, q = bx & 15;
  int h = hb / BB, b = hb % BB;
  int tr = q >> 2, tc = q & 3;
  int idx = h * LL + layer;
  const uint8_t* A = axpx + (size_t)hb * SS * DD + (size_t)(tr * 128) * DD;
  const uint8_t* Bm = wgb + (size_t)idx * DD * DD + (size_t)(tc * 128) * DD;
  f32x4 acc[4][4];
  #pragma unroll
  for (int m = 0; m < 4; m++)
    #pragma unroll
    for (int n = 0; n < 4; n++) acc[m][n] = (f32x4){0.f, 0.f, 0.f, 0.f};
  gemmf8(A, DD, Bm, DD, DD, lds, acc);
  int lane = threadIdx.x & 63, wid = threadIdx.x >> 6;
  int wr = wid >> 1, wc = wid & 1;
  int r4 = (lane >> 4) * 4, cn = lane & 15;
  #pragma unroll
  for (int m = 0; m < 4; m++) {
    #pragma unroll
    for (int n = 0; n < 4; n++) {
      int sb = tr*128 + wr*64 + m*16 + r4;
      int e = tc*128 + wc*64 + n*16 + cn;
      float vv[4];
      #pragma unroll
      for (int r = 0; r < 4; r++) {
        float v = (acc[m][n][r] * 0.0078125f + 2.0f * bg[(size_t)idx * DD + e])
                  * rden[(size_t)hb * SS + sb + r];
        vv[r] = fmaxf(v, 0.0f) * 64.0f;
      }
      uint32_t pk4 = 0;
      pk4 = __builtin_amdgcn_cvt_pk_fp8_f32(vv[0], vv[1], pk4, false);
      pk4 = __builtin_amdgcn_cvt_pk_fp8_f32(vv[2], vv[3], pk4, true);
      #pragma unroll
      for (int r = 0; r < 4; r++)
        finb[((size_t)b * SS + sb + r) * FF + (size_t)idx * DD + e] =
            (uint8_t)(pk4 >> (8 * r));
      if (layer == 0)
        *(uint32_t*)(yt + (size_t)hb * DD * SS + (size_t)e * SS + sb) = pk4;
    }
  }
}

// ---- kF (fp8, split-K=2): part[ks] = finb[:, ks*1536+..] @ wob[:, same]^T / 4096
__global__ __launch_bounds__(256, 4) void k_gemmF(
    const uint8_t* __restrict__ finb, const uint8_t* __restrict__ wob,
    short* __restrict__ part) {
  __shared__ uint8_t lds[32768];
  int bx = xswz(BB*16*2);          // 512 blocks
  int ks = bx >> 8;                // 0..1
  int q = bx & 255;
  int tr = q >> 2, tc = q & 3;     // tr 0..63, tc 0..3
  const uint8_t* A = finb + (size_t)(tr * 128) * FF + ks * 1536;
  const uint8_t* Bm = wob + (size_t)(tc * 128) * FF + ks * 1536;
  f32x4 acc[4][4];
  #pragma unroll
  for (int m = 0; m < 4; m++)
    #pragma unroll
    for (int n = 0; n < 4; n++) acc[m][n] = (f32x4){0.f, 0.f, 0.f, 0.f};
  gemmf8(A, FF, Bm, FF, 1536, lds, acc);
  int lane = threadIdx.x & 63, wid = threadIdx.x >> 6;
  int wr = wid >> 1, wc = wid & 1;
  int r4 = (lane >> 4) * 4, cn = lane & 15;
  short* op = part + (size_t)ks * ((size_t)BB*SS*DD);
  #pragma unroll
  for (int m = 0; m < 4; m++) {
    #pragma unroll
    for (int n = 0; n < 4; n++) {
      #pragma unroll
      for (int r = 0; r < 4; r++) {
        int row = tr*128 + wr*64 + m*16 + r4 + r;
        int d = tc*128 + wc*64 + n*16 + cn;
        op[(size_t)row * DD + d] = f2b(acc[m][n][r] * (1.0f / 4096.0f));
      }
    }
  }
}

// ---- reduce: out = x0 + b_out + part0 + part1   (bf16 parts, 8/thread)
__global__ void k_redF(const short* __restrict__ part, const float* __restrict__ x0f,
                       const float* __restrict__ bo, float* __restrict__ out) {
  const size_t PSZ = (size_t)BB * SS * DD;          // 4,194,304
  size_t i = ((size_t)blockIdx.x * 256 + threadIdx.x) * 8;
  if (i >= PSZ) return;
  int d = (int)(i & (DD - 1));
  bf16x8 q0 = *(const bf16x8*)(part + i);
  bf16x8 q1 = *(const bf16x8*)(part + PSZ + i);
  vfloat4 xa = *(const vfloat4*)(x0f + i);
  vfloat4 xb = *(const vfloat4*)(x0f + i + 4);
  vfloat4 ba = *(const vfloat4*)(bo + d);
  vfloat4 bb = *(const vfloat4*)(bo + d + 4);
  vfloat4 oa, ob;
  #pragma unroll
  for (int j = 0; j < 4; j++) {
    oa[j] = b2f(q0[j]) + b2f(q1[j]) + xa[j] + ba[j];
    ob[j] = b2f(q0[j+4]) + b2f(q1[j+4]) + xb[j] + bb[j];
  }
  *(vfloat4*)(out + i) = oa;
  *(vfloat4*)(out + i + 4) = ob;
}

extern "C" void kernel_launch(void* const* d_in, const int* in_sizes, int n_in,
                              void* d_out, int out_size, void* d_ws, size_t ws_size,
                              hipStream_t stream) {
  const float* adj = (const float*)d_in[0];
  const float* x0  = (const float*)d_in[1];
  // d_in[2], d_in[3]: mask / domain_mask — unused by the reference forward.
  const float* wg  = (const float*)d_in[4];
  const float* bg  = (const float*)d_in[5];
  const float* wo  = (const float*)d_in[6];
  const float* bo  = (const float*)d_in[7];
  float* out = (float*)d_out;

  char* p = (char*)d_ws;
  uint8_t* adjf8 = (uint8_t*)p; p += (size_t)HH*BB*SS*SS;   // 12,582,912
  uint8_t* x0t   = (uint8_t*)p; p += (size_t)BB*DD*SS;      //  4,194,304
  uint8_t* yt    = (uint8_t*)p; p += (size_t)HH*BB*DD*SS;   // 12,582,912
  uint8_t* axpx  = (uint8_t*)p; p += (size_t)HH*BB*SS*DD;   // 12,582,912
  uint8_t* finb  = (uint8_t*)p; p += (size_t)BB*SS*FF;      // 25,165,824
  uint8_t* wgb   = (uint8_t*)p; p += (size_t)HH*LL*DD*DD;   //  1,572,864
  uint8_t* wob   = (uint8_t*)p; p += (size_t)DD*FF;         //  1,572,864
  float*   rden  = (float*)p;   p += (size_t)HH*BB*SS*4;    //     98,304
  short*   x0b   = (short*)p;   p += (size_t)BB*SS*DD*2;    //  8,388,608
  // total ~78.7 MiB. split-K=2 bf16 parts (16.8 MB) overlay adjf8+x0t
  // (16.8 MB exactly) — both dead by gemmF time.
  short* part = (short*)d_ws;

  // prep: adj->fp8 + rden | W->fp8 | x0 transpose+cvt, one dispatch
  k_prep<<<6144 + 768 + BB*64, 256, 0, stream>>>(
      adj, adjf8, rden, wg, wo, wgb, wob, x0, x0t, x0b);

  // layer 0
  k_gemmA<<<HH*BB*16, 256, 0, stream>>>(adjf8, x0t, x0b, finb, 0, axpx);
  k_gemmB<<<HH*BB*16, 256, 0, stream>>>(axpx, wgb, bg, rden, 0, finb, yt);
  // layer 1 (gemmB layer-0 epilogue wrote yt = transposed fp8 x64 outputs)
  k_gemmA<<<HH*BB*16, 256, 0, stream>>>(adjf8, yt, x0b, finb, 1, axpx);
  k_gemmB<<<HH*BB*16, 256, 0, stream>>>(axpx, wgb, bg, rden, 1, finb, yt);
  // output projection (fp8, split-K=2) + fused reduce w/ bias + residual
  k_gemmF<<<BB*16*2, 256, 0, stream>>>(finb, wob, part);
  k_redF<<<2048, 256, 0, stream>>>(part, x0, bo, out);
}